// Round 1
// 1000.485 us; speedup vs baseline: 1.1803x; 1.1803x over previous
//
#include <hip/hip_runtime.h>
#include <hip/hip_bf16.h>

#define N_USERS 70000
#define N_ITEMS 30000
#define N_NODES 100000
#define RD 192      // R*D
#define EE 1600000
#define NE3 4800000
#define M3 300000   // 3 * N_NODES segments
#define NSUB 98     // ceil(100000/1024) row sub-buckets
#define NBUCK 294   // 3 * NSUB

// output element offsets (dtype-independent)
#define OFF_U    0
#define OFF_I    13440000
#define OFF_IZ   19200000   // zero row (item index 30000)
#define OFF_RELA 19200192
#define OFF_S1   19200384
#define OFF_S2   19270384

typedef __hip_bfloat16 bf16;
typedef unsigned long long u64;
typedef __attribute__((ext_vector_type(8))) short short8;
typedef __attribute__((ext_vector_type(8))) unsigned short ushort8;
typedef __attribute__((ext_vector_type(4))) float f32x4;

__device__ __forceinline__ float b2f(bf16 v) { return __bfloat162float(v); }

union bfbits { bf16 b; unsigned short u; };

__device__ __forceinline__ float bits2f(unsigned short u) {
  bfbits x; x.u = u; return b2f(x.b);
}
__device__ __forceinline__ unsigned short f2bits(float f) {
  bfbits x; x.b = __float2bfloat16(f); return x.u;
}

// dtype-adaptive IO: f32 -> fp32 arrays, else bf16 arrays
__device__ __forceinline__ float loadf(const void* p, int i, bool f32) {
  return f32 ? ((const float*)p)[i] : b2f(((const bf16*)p)[i]);
}
__device__ __forceinline__ void storef(void* p, int i, float v, bool f32) {
  if (f32) ((float*)p)[i] = v;
  else ((bf16*)p)[i] = __float2bfloat16(v);
}

__device__ __forceinline__ float wave_sum(float v) {
#pragma unroll
  for (int off = 32; off >= 1; off >>= 1) v += __shfl_xor(v, off, 64);
  return v;
}

__global__ void detect_kernel(const unsigned short* __restrict__ ue,
                              int* __restrict__ flag) {
  __shared__ int s;
  int t = threadIdx.x;
  if (t == 0) s = 0;
  __syncthreads();
  int big = 0;
  for (int j = t; j < 8192; j += 256) {
    int e = (ue[j] >> 7) & 0xFF;
    if (e >= 127) big = 1;
  }
  if (big) atomicOr(&s, 1);
  __syncthreads();
  if (t == 0) *flag = s;
}

__global__ void zero_row_kernel(void* out, const int* __restrict__ flag) {
  bool f32 = *flag != 0;
  storef(out, OFF_IZ + (int)threadIdx.x, 0.f, f32);  // 192 threads
}

// rela chain: rela0=rel_emb, rela1=rela0@W_rel[0], rela2=rela1@W_rel[1]
__global__ void rela_kernel(const void* __restrict__ rel_emb,
                            const void* __restrict__ W_rel,
                            const int* __restrict__ flag,
                            float* __restrict__ rela_f, void* out) {
  bool f32 = *flag != 0;
  __shared__ float r0s[192], r1s[192];
  int t = threadIdx.x;            // 192 threads
  int i = t >> 6, d = t & 63;
  float r0 = loadf(rel_emb, t, f32);
  r0s[t] = r0;
  __syncthreads();
  float acc = 0.f;
  for (int k = 0; k < 64; ++k)
    acc += r0s[i * 64 + k] * loadf(W_rel, k * 64 + d, f32);
  r1s[t] = acc;
  __syncthreads();
  float acc2 = 0.f;
  for (int k = 0; k < 64; ++k)
    acc2 += r1s[i * 64 + k] * loadf(W_rel, 4096 + k * 64 + d, f32);
  rela_f[t] = r0;
  rela_f[192 + t] = acc;
  rela_f[384 + t] = acc2;
  storef(out, OFF_RELA + t, (r0 + acc + acc2) * (1.f / 3.f), f32);
}

// vectorized x4: one thread converts 4 contiguous dims (never crosses 64-dim
// boundary since 4 | 64)
__global__ __launch_bounds__(256) void init_kernel(
    const void* __restrict__ user_emb, const void* __restrict__ item_emb,
    const int* __restrict__ flag, bf16* __restrict__ ego0) {
  bool f32 = *flag != 0;
  int idx4 = blockIdx.x * 256 + threadIdx.x;
  if (idx4 >= N_NODES * RD / 4) return;
  int idx = idx4 << 2;
  int n = idx / RD;
  int rd = idx - n * RD;
  int d = rd & 63;
  const void* src;
  int off;
  if (n < N_USERS) { src = user_emb; off = n * 64 + d; }
  else             { src = item_emb; off = (n - N_USERS) * 64 + d; }
  ushort4 o;
  if (f32) {
    float4 fv = *(const float4*)((const float*)src + off);
    o.x = f2bits(fv.x); o.y = f2bits(fv.y); o.z = f2bits(fv.z); o.w = f2bits(fv.w);
  } else {
    o = *(const ushort4*)((const unsigned short*)src + off);
  }
  *(ushort4*)(ego0 + idx) = o;
}

// ---- CSR build ----
__global__ __launch_bounds__(256) void hist_kernel(
    const int* __restrict__ rows, int* __restrict__ counts) {
  int idx = blockIdx.x * 256 + threadIdx.x;
  if (idx >= NE3) return;
  int i = idx / EE;
  atomicAdd(counts + i * N_NODES + rows[idx], 1);
}

// block-level exclusive scan (1024/block), writes block totals
__global__ __launch_bounds__(1024) void scanA_kernel(
    const int* __restrict__ counts, int* __restrict__ offs,
    int* __restrict__ bsums) {
  __shared__ int s[1024];
  int t = threadIdx.x;
  int idx = blockIdx.x * 1024 + t;
  int x = (idx < M3) ? counts[idx] : 0;
  s[t] = x;
  __syncthreads();
  for (int off = 1; off < 1024; off <<= 1) {
    int y = (t >= off) ? s[t - off] : 0;
    __syncthreads();
    s[t] += y;
    __syncthreads();
  }
  if (idx < M3) offs[idx] = s[t] - x;
  if (t == 1023) bsums[blockIdx.x] = s[t];
}

__global__ __launch_bounds__(512) void scanB_kernel(
    const int* __restrict__ bsums, int* __restrict__ bsums2, int nb) {
  __shared__ int s[512];
  int t = threadIdx.x;
  int x = (t < nb) ? bsums[t] : 0;
  s[t] = x;
  __syncthreads();
  for (int off = 1; off < 512; off <<= 1) {
    int y = (t >= off) ? s[t - off] : 0;
    __syncthreads();
    s[t] += y;
    __syncthreads();
  }
  if (t < nb) bsums2[t] = s[t] - x;
}

__global__ __launch_bounds__(1024) void scanC_kernel(
    int* __restrict__ offs, const int* __restrict__ bsums2) {
  int idx = blockIdx.x * 1024 + threadIdx.x;
  if (idx >= M3) return;
  offs[idx] += bsums2[blockIdx.x];
}

// bucket base cursors: gcursor[b] = offs[first row of bucket]
__global__ void binit_kernel(const int* __restrict__ offs,
                             int* __restrict__ gcursor) {
  int b = threadIdx.x;   // 512 threads
  if (b >= NBUCK) return;
  int rel = b / NSUB, sub = b - rel * NSUB;
  gcursor[b] = offs[rel * N_NODES + (sub << 10)];
}

// Pass A: bucket edges into 294 (rel, row>>10) buckets; runs are
// block-contiguous -> L2 coalesces lines. Packed u64: rowlo<<48|col<<16|bf16
__global__ __launch_bounds__(256) void passA_kernel(
    const int* __restrict__ rows, const int* __restrict__ cols,
    const void* __restrict__ vals, const int* __restrict__ flag,
    int* __restrict__ gcursor, u64* __restrict__ abuf) {
  bool f32 = *flag != 0;
  __shared__ u64 pk[4096];
  __shared__ unsigned short bk[4096];
  __shared__ int cnt[NBUCK], pos[NBUCK], gbase[NBUCK];
  int t = threadIdx.x;
  for (int j = t; j < NBUCK; j += 256) { cnt[j] = 0; pos[j] = 0; }
  __syncthreads();
  int base = blockIdx.x * 4096;
  int m = min(4096, NE3 - base);
  for (int j = t; j < m; j += 256) {
    int idx = base + j;
    int i = idx / EE;
    int r = rows[idx];
    int c = cols[idx];
    unsigned short vb =
        f32 ? f2bits(((const float*)vals)[idx])
            : ((const unsigned short*)vals)[idx];
    int sub = r >> 10;
    int b = i * NSUB + sub;
    pk[j] = ((u64)(r & 1023) << 48) | ((u64)(unsigned)c << 16) | vb;
    bk[j] = (unsigned short)b;
    atomicAdd(&cnt[b], 1);
  }
  __syncthreads();
  for (int j = t; j < NBUCK; j += 256)
    if (cnt[j] > 0) gbase[j] = atomicAdd(&gcursor[j], cnt[j]);
  __syncthreads();
  for (int j = t; j < m; j += 256) {
    int b = bk[j];
    int p = atomicAdd(&pos[b], 1);
    abuf[gbase[b] + p] = pk[j];
  }
}

// Pass B: one block per bucket; LDS row cursors; dest range ~130KB contiguous
// sedge payload: .x = precomputed ego BYTE offset (col*384 + rel*128),
//                .y = f32 edge weight bits
__global__ __launch_bounds__(256) void passB_kernel(
    const u64* __restrict__ abuf, const int* __restrict__ offs,
    int2* __restrict__ sedge) {
  __shared__ int curs[1024];
  int b = blockIdx.x;
  int rel = b / NSUB, sub = b - rel * NSUB;
  int r0 = sub << 10;
  int nr = min(1024, N_NODES - r0);
  int gi = rel * N_NODES + r0;
  int t = threadIdx.x;
  for (int j = t; j < nr; j += 256) curs[j] = offs[gi + j];
  __syncthreads();
  int base = offs[gi];
  int endi = gi + nr;
  int end = (endi < M3) ? offs[endi] : NE3;
  int rbase = rel * 128;
  for (int e = base + t; e < end; e += 256) {
    u64 w = abuf[e];
    int rowlo = (int)(w >> 48);
    int c = (int)((w >> 16) & 0x3FFFF);
    float v = bits2f((unsigned short)(w & 0xFFFF));
    int p = atomicAdd(&curs[rowlo], 1);
    int2 eo; eo.x = c * 384 + rbase; eo.y = __float_as_int(v);
    sedge[p] = eo;
  }
}

// one wave per (node, relation) segment. Pair-packed loads: lanes 0-31 fetch
// even edge's 128B ego line, lanes 32-63 the odd edge's line; each lane loads
// one dword (2 bf16 dims). 8 pair-instructions per batch = 16 lines in flight
// per wave. Edge headers carry precomputed byte offsets + f32 weight, so the
// inner loop is ~4 VALU/edge. Halves combined with one shfl_xor(32).
__global__ __launch_bounds__(256, 8) void gather_kernel(
    const int2* __restrict__ sedge, const int* __restrict__ counts,
    const int* __restrict__ offs, const bf16* __restrict__ ego,
    bf16* __restrict__ prop) {
  int seg = blockIdx.x * 4 + (threadIdx.x >> 6);   // i*N_NODES + n
  int lane = threadIdx.x & 63;
  int half = lane >> 5;        // 0: even edge of pair, 1: odd edge
  int k = lane & 31;           // dim-pair index: dims 2k, 2k+1
  int voff = k << 2;           // byte offset within the 128B line
  int i = seg / N_NODES;
  int n = seg - i * N_NODES;
  int base = offs[seg];
  int cnt = counts[seg];
  const char* egob = (const char*)ego;
  float acc0 = 0.f, acc1 = 0.f;
  int j = 0;
  for (; j + 16 <= cnt; j += 16) {
    int2 h[8];
    unsigned d[8];
#pragma unroll
    for (int u = 0; u < 8; ++u) h[u] = sedge[base + j + 2 * u + half];
#pragma unroll
    for (int u = 0; u < 8; ++u)
      d[u] = *(const unsigned*)(egob + (size_t)((unsigned)h[u].x + voff));
#pragma unroll
    for (int u = 0; u < 8; ++u) {
      float vv = __int_as_float(h[u].y);
      acc0 = fmaf(__int_as_float(d[u] << 16), vv, acc0);
      acc1 = fmaf(__int_as_float(d[u] & 0xffff0000u), vv, acc1);
    }
  }
  // tail: up to 15 edges as one masked parallel batch (np pairs, wave-uniform)
  int rem = cnt - j;
  if (rem > 0) {
    int np = (rem + 1) >> 1;   // 1..8
    int2 h[8];
    unsigned d[8];
#pragma unroll
    for (int u = 0; u < 8; ++u)
      if (u < np) {
        int idx = 2 * u + half;
        h[u] = sedge[base + j + (idx < rem ? idx : rem - 1)];
      }
#pragma unroll
    for (int u = 0; u < 8; ++u)
      if (u < np)
        d[u] = *(const unsigned*)(egob + (size_t)((unsigned)h[u].x + voff));
#pragma unroll
    for (int u = 0; u < 8; ++u)
      if (u < np) {
        float vv = (2 * u + half < rem) ? __int_as_float(h[u].y) : 0.f;
        acc0 = fmaf(__int_as_float(d[u] << 16), vv, acc0);
        acc1 = fmaf(__int_as_float(d[u] & 0xffff0000u), vv, acc1);
      }
  }
  acc0 += __shfl_xor(acc0, 32, 64);
  acc1 += __shfl_xor(acc1, 32, 64);
  if (half == 0) {
    unsigned lo = f2bits(acc0);
    unsigned hi = f2bits(acc1);
    *(unsigned*)((char*)prop + (size_t)(n * RD + i * 64) * 2 + voff) =
        lo | (hi << 16);
  }
}

__device__ __forceinline__ float attn_row(float a, float b, float c,
                                          float e0, float e1, float e2) {
  float m = fmaxf(a, fmaxf(b, c));
  float w0 = __expf(a - m), w1 = __expf(b - m), w2 = __expf(c - m);
  float inv = 1.f / (w0 + w1 + w2);
  return (w0 * e0 + w1 * e1 + w2 * e2) * inv;
}

// MFMA transform: X(300000x64) @ W(64x64), X = prop * rela (per-relation).
// Block = 64 nodes = 192 X-rows. Wave w owns W cols [16w,16w+16).
// 12 row-tiles x 2 mfma_16x16x32_bf16. est -> LDS (stride 66) -> 3x3 attn.
__global__ __launch_bounds__(256) void transform_attn_kernel(
    const bf16* __restrict__ prop, const float* __restrict__ rela_k,
    const void* __restrict__ Wgc, int wgc_off, const int* __restrict__ flag,
    bf16* __restrict__ ego_out) {
  bool f32 = *flag != 0;
  __shared__ float est_s[192 * 66];
  int t = threadIdx.x, lane = t & 63, wave = t >> 6;
  int quad = lane >> 4, m = lane & 15;
  int wcol = wave * 16 + m;   // this lane's D column (global 0..63)
  // B fragments (one-time): B[k=quad*8+j][n=wcol]
  short8 b0, b1;
#pragma unroll
  for (int j = 0; j < 8; ++j) {
    int k0 = quad * 8 + j;
    b0[j] = (short)f2bits(loadf(Wgc, wgc_off + k0 * 64 + wcol, f32));
    b1[j] = (short)f2bits(loadf(Wgc, wgc_off + (k0 + 32) * 64 + wcol, f32));
  }
  // rela values at this lane's k positions, for all 3 relations
  float relv0[16], relv1[16], relv2[16];
#pragma unroll
  for (int j = 0; j < 8; ++j) {
    int k0 = quad * 8 + j;
    relv0[j] = rela_k[k0];        relv0[8 + j] = rela_k[32 + k0];
    relv1[j] = rela_k[64 + k0];   relv1[8 + j] = rela_k[96 + k0];
    relv2[j] = rela_k[128 + k0];  relv2[8 + j] = rela_k[160 + k0];
  }
  int n0 = blockIdx.x * 64;
  int row0 = n0 * 3;
#pragma unroll
  for (int tr = 0; tr < 12; ++tr) {
    int rl = tr * 16 + m;            // local A row
    int row = row0 + rl;
    int row_c = row < M3 ? row : 0;
    int i = rl % 3;                  // relation of this row (row0 % 3 == 0)
    const ushort8* pp = (const ushort8*)(prop + (size_t)row_c * 64 + quad * 8);
    ushort8 x0 = pp[0];              // k = quad*8 .. +7
    ushort8 x1 = pp[4];              // k+32
    short8 a0, a1;
#pragma unroll
    for (int j = 0; j < 8; ++j) {
      float r0 = (i == 0) ? relv0[j] : (i == 1 ? relv1[j] : relv2[j]);
      float r1 = (i == 0) ? relv0[8 + j] : (i == 1 ? relv1[8 + j] : relv2[8 + j]);
      a0[j] = (short)f2bits(bits2f(x0[j]) * r0);
      a1[j] = (short)f2bits(bits2f(x1[j]) * r1);
    }
    f32x4 acc = {0.f, 0.f, 0.f, 0.f};
    acc = __builtin_amdgcn_mfma_f32_16x16x32_bf16(a0, b0, acc, 0, 0, 0);
    acc = __builtin_amdgcn_mfma_f32_16x16x32_bf16(a1, b1, acc, 0, 0, 0);
#pragma unroll
    for (int r = 0; r < 4; ++r) {
      float v = acc[r];
      v = v > 0.f ? v : 0.01f * v;   // leaky relu
      est_s[(tr * 16 + quad * 4 + r) * 66 + wcol] = v;
    }
  }
  __syncthreads();
  const float sc = 0.088388347648318447f;  // 1/sqrt(128)
  for (int jj = 0; jj < 16; ++jj) {
    int nl = wave * 16 + jj;
    int n = n0 + nl;
    if (n >= N_NODES) break;
    float e0 = est_s[(3 * nl + 0) * 66 + lane];
    float e1 = est_s[(3 * nl + 1) * 66 + lane];
    float e2 = est_s[(3 * nl + 2) * 66 + lane];
    float s00 = wave_sum(e0 * e0);
    float s01 = wave_sum(e0 * e1);
    float s02 = wave_sum(e0 * e2);
    float s11 = wave_sum(e1 * e1);
    float s12 = wave_sum(e1 * e2);
    float s22 = wave_sum(e2 * e2);
    float o0 = attn_row(s00 * sc, s01 * sc, s02 * sc, e0, e1, e2);
    float o1 = attn_row(s01 * sc, s11 * sc, s12 * sc, e0, e1, e2);
    float o2 = attn_row(s02 * sc, s12 * sc, s22 * sc, e0, e1, e2);
    int base = n * RD + lane;
    ego_out[base] = __float2bfloat16(o0);
    ego_out[base + 64] = __float2bfloat16(o1);
    ego_out[base + 128] = __float2bfloat16(o2);
  }
}

// final: attention row 2, outputs, and MFMA GRU + scores.
// Block = 64 nodes. fmat row = i*64 + node_local, stride 66.
__global__ __launch_bounds__(256) void final_kernel(
    const bf16* __restrict__ ego0, const bf16* __restrict__ ego1,
    const bf16* __restrict__ ego2, const void* __restrict__ gru_w,
    const void* __restrict__ gru_b, const void* __restrict__ tra,
    const int* __restrict__ flag, void* out) {
  bool f32 = *flag != 0;
  __shared__ float fmat[192 * 66];
  __shared__ float sc_lds[128];   // [64 nodes][2]
  int t = threadIdx.x, lane = t & 63, wave = t >> 6;
  int quad = lane >> 4, m = lane & 15;
  int wcol = wave * 16 + m;
  if (t < 128) sc_lds[t] = 0.f;
  // B-frags for gru_w[0..2]; biases; tra scalars (per-lane)
  short8 bw[3][2];
#pragma unroll
  for (int i = 0; i < 3; ++i)
#pragma unroll
    for (int j = 0; j < 8; ++j) {
      int k0 = quad * 8 + j;
      bw[i][0][j] = (short)f2bits(loadf(gru_w, i * 4096 + k0 * 64 + wcol, f32));
      bw[i][1][j] =
          (short)f2bits(loadf(gru_w, i * 4096 + (k0 + 32) * 64 + wcol, f32));
    }
  float bias0 = loadf(gru_b, wcol, f32);
  float bias1 = loadf(gru_b, 64 + wcol, f32);
  float bias2 = loadf(gru_b, 128 + wcol, f32);
  float ts0 = loadf(tra, wcol, f32);        // tra[0][:64]   (tgt -> sc1)
  float ts1 = loadf(tra, 64 + wcol, f32);   // tra[0][64:]   (aux1 -> sc1)
  float ts2 = loadf(tra, 128 + wcol, f32);  // tra[1][:64]   (tgt -> sc2)
  float ts3 = loadf(tra, 192 + wcol, f32);  // tra[1][64:]   (aux2 -> sc2)

  int n0 = blockIdx.x * 64;
  // Phase 1: attention + u/i outputs + fmat
  for (int jj = 0; jj < 16; ++jj) {
    int nl = wave * 16 + jj;
    int n = n0 + nl;
    float f0 = 0.f, f1 = 0.f, f2 = 0.f;
    if (n < N_NODES) {
      int b0i = n * RD + lane;
      float a0 = b2f(ego0[b0i]) + b2f(ego1[b0i]) + b2f(ego2[b0i]);
      float a1 =
          b2f(ego0[b0i + 64]) + b2f(ego1[b0i + 64]) + b2f(ego2[b0i + 64]);
      float a2 =
          b2f(ego0[b0i + 128]) + b2f(ego1[b0i + 128]) + b2f(ego2[b0i + 128]);
      float s20 = wave_sum(a2 * a0);
      float s21 = wave_sum(a2 * a1);
      float s22 = wave_sum(a2 * a2);
      float mid2 = attn_row(s20, s21, s22, a0, a1, a2);
      f0 = a0 * (1.f / 3.f);
      f1 = a1 * (1.f / 3.f);
      f2 = mid2 * (1.f / 3.f);
      if (n < N_USERS) {
        int ob = OFF_U + n * RD + lane;
        storef(out, ob, f0, f32);
        storef(out, ob + 64, f1, f32);
        storef(out, ob + 128, f2, f32);
      } else {
        int ob = OFF_I + (n - N_USERS) * RD + lane;
        storef(out, ob, f0, f32);
        storef(out, ob + 64, f1, f32);
        storef(out, ob + 128, f2, f32);
      }
    }
    fmat[(0 * 64 + nl) * 66 + lane] = f0;
    fmat[(1 * 64 + nl) * 66 + lane] = f1;
    fmat[(2 * 64 + nl) * 66 + lane] = f2;
  }
  __syncthreads();
  // Phase 2: 3 GEMMs (64x64 @ 64x64) + score partials
#pragma unroll
  for (int i = 0; i < 3; ++i) {
    float bias = (i == 0) ? bias0 : (i == 1 ? bias1 : bias2);
#pragma unroll
    for (int tr = 0; tr < 4; ++tr) {
      int arow = (i * 64 + tr * 16 + m) * 66;
      short8 a0, a1;
#pragma unroll
      for (int j = 0; j < 8; ++j) {
        a0[j] = (short)f2bits(fmat[arow + quad * 8 + j]);
        a1[j] = (short)f2bits(fmat[arow + quad * 8 + j + 32]);
      }
      f32x4 acc = {0.f, 0.f, 0.f, 0.f};
      acc = __builtin_amdgcn_mfma_f32_16x16x32_bf16(a0, bw[i][0], acc, 0, 0, 0);
      acc = __builtin_amdgcn_mfma_f32_16x16x32_bf16(a1, bw[i][1], acc, 0, 0, 0);
#pragma unroll
      for (int r = 0; r < 4; ++r) {
        int nl = tr * 16 + quad * 4 + r;
        float y = acc[r] + bias;
        float f = fmat[(i * 64 + nl) * 66 + wcol];
        float prod = f * y;
        float p1 = 0.f, p2 = 0.f;
        if (i == 0) p1 = prod * ts1;
        else if (i == 1) p2 = prod * ts3;
        else { p1 = prod * ts0; p2 = prod * ts2; }
        // reduce over 16 cols (m-lanes, stays within quad)
#pragma unroll
        for (int off = 1; off < 16; off <<= 1) {
          p1 += __shfl_xor(p1, off, 64);
          p2 += __shfl_xor(p2, off, 64);
        }
        if (m == 0) {
          if (i != 1) atomicAdd(&sc_lds[nl * 2], p1);
          if (i != 0) atomicAdd(&sc_lds[nl * 2 + 1], p2);
        }
      }
    }
  }
  __syncthreads();
  // Phase 3: score outputs
  if (t < 64) {
    int n = n0 + t;
    if (n < N_USERS) {
      storef(out, OFF_S1 + n, sc_lds[t * 2], f32);
      storef(out, OFF_S2 + n, sc_lds[t * 2 + 1], f32);
    }
  }
}

extern "C" void kernel_launch(void* const* d_in, const int* in_sizes, int n_in,
                              void* d_out, int out_size, void* d_ws,
                              size_t ws_size, hipStream_t stream) {
  const void* user_emb = d_in[0];
  const void* item_emb = d_in[1];
  const void* rel_emb = d_in[2];
  const void* W_gc = d_in[3];
  const void* W_rel = d_in[4];
  const void* gru_w = d_in[5];
  const void* gru_b = d_in[6];
  const void* tra = d_in[7];
  const void* adj_vals = d_in[8];
  const int* adj_rows = (const int*)d_in[9];
  const int* adj_cols = (const int*)d_in[10];

  // ws layout (~156 MB)
  int* flag = (int*)d_ws;
  float* wsf = (float*)d_ws;
  float* rela_f = wsf + 16;                       // 576 floats
  int* counts = (int*)(wsf + 1024);               // 300k
  int* offs = counts + M3;                        // 300k
  int* gcursor = offs + M3;                       // 512
  int* bsums = gcursor + 512;                     // 1024
  int* bsums2 = bsums + 1024;                     // 1024
  u64* abuf = (u64*)(bsums2 + 1024);              // 4.8M u64 (8B-aligned)
  int2* sedge = (int2*)(abuf + NE3);              // 4.8M int2
  bf16* ego0 = (bf16*)(sedge + NE3);              // 19.2M bf16
  bf16* ego1 = ego0 + (size_t)N_NODES * RD;
  bf16* ego2 = ego1 + (size_t)N_NODES * RD;
  bf16* prop = ego2 + (size_t)N_NODES * RD;

  const int nbScan = (M3 + 1023) / 1024;          // 293

  detect_kernel<<<1, 256, 0, stream>>>((const unsigned short*)user_emb, flag);
  rela_kernel<<<1, 192, 0, stream>>>(rel_emb, W_rel, flag, rela_f, d_out);
  zero_row_kernel<<<1, 192, 0, stream>>>(d_out, flag);
  init_kernel<<<(N_NODES * RD / 4 + 255) / 256, 256, 0, stream>>>(
      user_emb, item_emb, flag, ego0);

  (void)hipMemsetAsync(counts, 0, (size_t)M3 * sizeof(int), stream);
  hist_kernel<<<(NE3 + 255) / 256, 256, 0, stream>>>(adj_rows, counts);
  scanA_kernel<<<nbScan, 1024, 0, stream>>>(counts, offs, bsums);
  scanB_kernel<<<1, 512, 0, stream>>>(bsums, bsums2, nbScan);
  scanC_kernel<<<nbScan, 1024, 0, stream>>>(offs, bsums2);
  binit_kernel<<<1, 512, 0, stream>>>(offs, gcursor);
  passA_kernel<<<(NE3 + 4095) / 4096, 256, 0, stream>>>(
      adj_rows, adj_cols, adj_vals, flag, gcursor, abuf);
  passB_kernel<<<NBUCK, 256, 0, stream>>>(abuf, offs, sedge);

  gather_kernel<<<M3 / 4, 256, 0, stream>>>(sedge, counts, offs, ego0, prop);
  transform_attn_kernel<<<(N_NODES + 63) / 64, 256, 0, stream>>>(
      prop, rela_f, W_gc, 0, flag, ego1);
  gather_kernel<<<M3 / 4, 256, 0, stream>>>(sedge, counts, offs, ego1, prop);
  transform_attn_kernel<<<(N_NODES + 63) / 64, 256, 0, stream>>>(
      prop, rela_f + 192, W_gc, 4096, flag, ego2);

  final_kernel<<<(N_NODES + 63) / 64, 256, 0, stream>>>(
      ego0, ego1, ego2, gru_w, gru_b, tra, flag, d_out);
}

// Round 2
// 839.305 us; speedup vs baseline: 1.4070x; 1.1920x over previous
//
#include <hip/hip_runtime.h>
#include <hip/hip_bf16.h>

#define N_USERS 70000
#define N_ITEMS 30000
#define N_NODES 100000
#define RD 192      // R*D
#define EE 1600000
#define NE3 4800000
#define M3 300000   // 3 * N_NODES segments
#define NSUB 98     // ceil(100000/1024) row sub-buckets
#define NBUCK 294   // 3 * NSUB

// output element offsets (dtype-independent)
#define OFF_U    0
#define OFF_I    13440000
#define OFF_IZ   19200000   // zero row (item index 30000)
#define OFF_RELA 19200192
#define OFF_S1   19200384
#define OFF_S2   19270384

typedef __hip_bfloat16 bf16;
typedef unsigned long long u64;
typedef __attribute__((ext_vector_type(8))) short short8;
typedef __attribute__((ext_vector_type(8))) unsigned short ushort8;
typedef __attribute__((ext_vector_type(4))) float f32x4;

__device__ __forceinline__ float b2f(bf16 v) { return __bfloat162float(v); }

union bfbits { bf16 b; unsigned short u; };

__device__ __forceinline__ float bits2f(unsigned short u) {
  bfbits x; x.u = u; return b2f(x.b);
}
__device__ __forceinline__ unsigned short f2bits(float f) {
  bfbits x; x.b = __float2bfloat16(f); return x.u;
}

// dtype-adaptive IO: f32 -> fp32 arrays, else bf16 arrays
__device__ __forceinline__ float loadf(const void* p, int i, bool f32) {
  return f32 ? ((const float*)p)[i] : b2f(((const bf16*)p)[i]);
}
__device__ __forceinline__ void storef(void* p, int i, float v, bool f32) {
  if (f32) ((float*)p)[i] = v;
  else ((bf16*)p)[i] = __float2bfloat16(v);
}

__device__ __forceinline__ float wave_sum(float v) {
#pragma unroll
  for (int off = 32; off >= 1; off >>= 1) v += __shfl_xor(v, off, 64);
  return v;
}

__global__ void detect_kernel(const unsigned short* __restrict__ ue,
                              int* __restrict__ flag) {
  __shared__ int s;
  int t = threadIdx.x;
  if (t == 0) s = 0;
  __syncthreads();
  int big = 0;
  for (int j = t; j < 8192; j += 256) {
    int e = (ue[j] >> 7) & 0xFF;
    if (e >= 127) big = 1;
  }
  if (big) atomicOr(&s, 1);
  __syncthreads();
  if (t == 0) *flag = s;
}

__global__ void zero_row_kernel(void* out, const int* __restrict__ flag) {
  bool f32 = *flag != 0;
  storef(out, OFF_IZ + (int)threadIdx.x, 0.f, f32);  // 192 threads
}

// rela chain: rela0=rel_emb, rela1=rela0@W_rel[0], rela2=rela1@W_rel[1]
__global__ void rela_kernel(const void* __restrict__ rel_emb,
                            const void* __restrict__ W_rel,
                            const int* __restrict__ flag,
                            float* __restrict__ rela_f, void* out) {
  bool f32 = *flag != 0;
  __shared__ float r0s[192], r1s[192];
  int t = threadIdx.x;            // 192 threads
  int i = t >> 6, d = t & 63;
  float r0 = loadf(rel_emb, t, f32);
  r0s[t] = r0;
  __syncthreads();
  float acc = 0.f;
  for (int k = 0; k < 64; ++k)
    acc += r0s[i * 64 + k] * loadf(W_rel, k * 64 + d, f32);
  r1s[t] = acc;
  __syncthreads();
  float acc2 = 0.f;
  for (int k = 0; k < 64; ++k)
    acc2 += r1s[i * 64 + k] * loadf(W_rel, 4096 + k * 64 + d, f32);
  rela_f[t] = r0;
  rela_f[192 + t] = acc;
  rela_f[384 + t] = acc2;
  storef(out, OFF_RELA + t, (r0 + acc + acc2) * (1.f / 3.f), f32);
}

// vectorized x4: one thread converts 4 contiguous dims (never crosses 64-dim
// boundary since 4 | 64)
__global__ __launch_bounds__(256) void init_kernel(
    const void* __restrict__ user_emb, const void* __restrict__ item_emb,
    const int* __restrict__ flag, bf16* __restrict__ ego0) {
  bool f32 = *flag != 0;
  int idx4 = blockIdx.x * 256 + threadIdx.x;
  if (idx4 >= N_NODES * RD / 4) return;
  int idx = idx4 << 2;
  int n = idx / RD;
  int rd = idx - n * RD;
  int d = rd & 63;
  const void* src;
  int off;
  if (n < N_USERS) { src = user_emb; off = n * 64 + d; }
  else             { src = item_emb; off = (n - N_USERS) * 64 + d; }
  ushort4 o;
  if (f32) {
    float4 fv = *(const float4*)((const float*)src + off);
    o.x = f2bits(fv.x); o.y = f2bits(fv.y); o.z = f2bits(fv.z); o.w = f2bits(fv.w);
  } else {
    o = *(const ushort4*)((const unsigned short*)src + off);
  }
  *(ushort4*)(ego0 + idx) = o;
}

// ---- CSR build (hierarchical; no 300K global-atomic histogram) ----
// Stage 1: per-block LDS histogram of the 294 (rel, row>>10) buckets.
__global__ __launch_bounds__(256) void bhist_kernel(
    const int* __restrict__ rows, int* __restrict__ bcnt) {
  __shared__ int h[NBUCK];
  int t = threadIdx.x;
  for (int j = t; j < NBUCK; j += 256) h[j] = 0;
  __syncthreads();
  int base = blockIdx.x * 4096;
  int m = min(4096, NE3 - base);
  for (int j = t; j < m; j += 256) {
    int idx = base + j;
    int i = idx / EE;
    int r = rows[idx];
    atomicAdd(&h[i * NSUB + (r >> 10)], 1);
  }
  __syncthreads();
  for (int j = t; j < NBUCK; j += 256)
    if (h[j]) atomicAdd(&bcnt[j], h[j]);
}

// Stage 2: exclusive scan of 294 bucket counts -> bucket bases.
// Writes both gcursor (mutated by passA) and bbase (read by passB).
__global__ __launch_bounds__(512) void bscan_kernel(
    const int* __restrict__ bcnt, int* __restrict__ gcursor,
    int* __restrict__ bbase) {
  __shared__ int s[512];
  int t = threadIdx.x;
  int x = (t < NBUCK) ? bcnt[t] : 0;
  s[t] = x;
  __syncthreads();
  for (int off = 1; off < 512; off <<= 1) {
    int y = (t >= off) ? s[t - off] : 0;
    __syncthreads();
    s[t] += y;
    __syncthreads();
  }
  if (t < NBUCK) {
    int e = s[t] - x;
    gcursor[t] = e;
    bbase[t] = e;
  }
}

// Pass A: bucket edges into 294 (rel, row>>10) buckets; runs are
// block-contiguous -> L2 coalesces lines. Packed u64: rowlo<<48|col<<16|bf16
__global__ __launch_bounds__(256) void passA_kernel(
    const int* __restrict__ rows, const int* __restrict__ cols,
    const void* __restrict__ vals, const int* __restrict__ flag,
    int* __restrict__ gcursor, u64* __restrict__ abuf) {
  bool f32 = *flag != 0;
  __shared__ u64 pk[4096];
  __shared__ unsigned short bk[4096];
  __shared__ int cnt[NBUCK], pos[NBUCK], gbase[NBUCK];
  int t = threadIdx.x;
  for (int j = t; j < NBUCK; j += 256) { cnt[j] = 0; pos[j] = 0; }
  __syncthreads();
  int base = blockIdx.x * 4096;
  int m = min(4096, NE3 - base);
  for (int j = t; j < m; j += 256) {
    int idx = base + j;
    int i = idx / EE;
    int r = rows[idx];
    int c = cols[idx];
    unsigned short vb =
        f32 ? f2bits(((const float*)vals)[idx])
            : ((const unsigned short*)vals)[idx];
    int sub = r >> 10;
    int b = i * NSUB + sub;
    pk[j] = ((u64)(r & 1023) << 48) | ((u64)(unsigned)c << 16) | vb;
    bk[j] = (unsigned short)b;
    atomicAdd(&cnt[b], 1);
  }
  __syncthreads();
  for (int j = t; j < NBUCK; j += 256)
    if (cnt[j] > 0) gbase[j] = atomicAdd(&gcursor[j], cnt[j]);
  __syncthreads();
  for (int j = t; j < m; j += 256) {
    int b = bk[j];
    int p = atomicAdd(&pos[b], 1);
    abuf[gbase[b] + p] = pk[j];
  }
}

// Pass B: one block per bucket. Builds the within-bucket row CSR in LDS
// (1024-bin histogram + scan over the bucket's edges), writes offs/counts
// for its contiguous segment range, then scatters edges to sedge.
// sedge payload: .x = precomputed ego BYTE offset (col*384 + rel*128),
//                .y = f32 edge weight bits
__global__ __launch_bounds__(256) void passB_kernel(
    const u64* __restrict__ abuf, const int* __restrict__ bbase,
    const int* __restrict__ bcnt, int* __restrict__ offs,
    int* __restrict__ counts, int2* __restrict__ sedge) {
  __shared__ int hist[1024];   // per-row counts, then global cursors
  __shared__ int s[256];
  int b = blockIdx.x;
  int rel = b / NSUB, sub = b - rel * NSUB;
  int r0 = sub << 10;
  int nr = min(1024, N_NODES - r0);   // 1024 or 672; always %4==0
  int gi = rel * N_NODES + r0;
  int t = threadIdx.x;
  for (int j = t; j < 1024; j += 256) hist[j] = 0;
  __syncthreads();
  int start = bbase[b];
  int cnt = bcnt[b];
  int end = start + cnt;
  for (int e = start + t; e < end; e += 256)
    atomicAdd(&hist[(int)(abuf[e] >> 48)], 1);
  __syncthreads();
  // exclusive scan over 1024 bins: 4 sequential per thread + 256-wide scan
  int j0 = t << 2;
  int a0 = hist[j0], a1 = hist[j0 + 1], a2 = hist[j0 + 2], a3 = hist[j0 + 3];
  int lsum = a0 + a1 + a2 + a3;
  s[t] = lsum;
  __syncthreads();
  for (int off = 1; off < 256; off <<= 1) {
    int y = (t >= off) ? s[t - off] : 0;
    __syncthreads();
    s[t] += y;
    __syncthreads();
  }
  int o0 = start + s[t] - lsum;
  int o1 = o0 + a0, o2 = o1 + a1, o3 = o2 + a2;
  // all hist reads completed before the scan barriers -> safe to overwrite
  hist[j0] = o0; hist[j0 + 1] = o1; hist[j0 + 2] = o2; hist[j0 + 3] = o3;
  if (j0 < nr) {
    *(int4*)(offs + gi + j0) = make_int4(o0, o1, o2, o3);
    *(int4*)(counts + gi + j0) = make_int4(a0, a1, a2, a3);
  }
  __syncthreads();
  int rbase = rel * 128;
  for (int e = start + t; e < end; e += 256) {
    u64 w = abuf[e];
    int rowlo = (int)(w >> 48);
    int c = (int)((w >> 16) & 0x3FFFF);
    float v = bits2f((unsigned short)(w & 0xFFFF));
    int p = atomicAdd(&hist[rowlo], 1);
    int2 eo; eo.x = c * 384 + rbase; eo.y = __float_as_int(v);
    sedge[p] = eo;
  }
}

// one wave per (node, relation) segment. Pair-packed loads: lanes 0-31 fetch
// even edge's 128B ego line, lanes 32-63 the odd edge's line; each lane loads
// one dword (2 bf16 dims). 8 pair-instructions per batch = 16 lines in flight
// per wave. Edge headers carry precomputed byte offsets + f32 weight, so the
// inner loop is ~4 VALU/edge. Halves combined with one shfl_xor(32).
__global__ __launch_bounds__(256, 8) void gather_kernel(
    const int2* __restrict__ sedge, const int* __restrict__ counts,
    const int* __restrict__ offs, const bf16* __restrict__ ego,
    bf16* __restrict__ prop) {
  int seg = blockIdx.x * 4 + (threadIdx.x >> 6);   // i*N_NODES + n
  int lane = threadIdx.x & 63;
  int half = lane >> 5;        // 0: even edge of pair, 1: odd edge
  int k = lane & 31;           // dim-pair index: dims 2k, 2k+1
  int voff = k << 2;           // byte offset within the 128B line
  int i = seg / N_NODES;
  int n = seg - i * N_NODES;
  int base = offs[seg];
  int cnt = counts[seg];
  const char* egob = (const char*)ego;
  float acc0 = 0.f, acc1 = 0.f;
  int j = 0;
  for (; j + 16 <= cnt; j += 16) {
    int2 h[8];
    unsigned d[8];
#pragma unroll
    for (int u = 0; u < 8; ++u) h[u] = sedge[base + j + 2 * u + half];
#pragma unroll
    for (int u = 0; u < 8; ++u)
      d[u] = *(const unsigned*)(egob + (size_t)((unsigned)h[u].x + voff));
#pragma unroll
    for (int u = 0; u < 8; ++u) {
      float vv = __int_as_float(h[u].y);
      acc0 = fmaf(__int_as_float(d[u] << 16), vv, acc0);
      acc1 = fmaf(__int_as_float(d[u] & 0xffff0000u), vv, acc1);
    }
  }
  // tail: up to 15 edges as one masked parallel batch (np pairs, wave-uniform)
  int rem = cnt - j;
  if (rem > 0) {
    int np = (rem + 1) >> 1;   // 1..8
    int2 h[8];
    unsigned d[8];
#pragma unroll
    for (int u = 0; u < 8; ++u)
      if (u < np) {
        int idx = 2 * u + half;
        h[u] = sedge[base + j + (idx < rem ? idx : rem - 1)];
      }
#pragma unroll
    for (int u = 0; u < 8; ++u)
      if (u < np)
        d[u] = *(const unsigned*)(egob + (size_t)((unsigned)h[u].x + voff));
#pragma unroll
    for (int u = 0; u < 8; ++u)
      if (u < np) {
        float vv = (2 * u + half < rem) ? __int_as_float(h[u].y) : 0.f;
        acc0 = fmaf(__int_as_float(d[u] << 16), vv, acc0);
        acc1 = fmaf(__int_as_float(d[u] & 0xffff0000u), vv, acc1);
      }
  }
  acc0 += __shfl_xor(acc0, 32, 64);
  acc1 += __shfl_xor(acc1, 32, 64);
  if (half == 0) {
    unsigned lo = f2bits(acc0);
    unsigned hi = f2bits(acc1);
    *(unsigned*)((char*)prop + (size_t)(n * RD + i * 64) * 2 + voff) =
        lo | (hi << 16);
  }
}

__device__ __forceinline__ float attn_row(float a, float b, float c,
                                          float e0, float e1, float e2) {
  float m = fmaxf(a, fmaxf(b, c));
  float w0 = __expf(a - m), w1 = __expf(b - m), w2 = __expf(c - m);
  float inv = 1.f / (w0 + w1 + w2);
  return (w0 * e0 + w1 * e1 + w2 * e2) * inv;
}

// MFMA transform: X(300000x64) @ W(64x64), X = prop * rela (per-relation).
// Block = 64 nodes = 192 X-rows. Wave w owns W cols [16w,16w+16).
// 12 row-tiles x 2 mfma_16x16x32_bf16. est -> LDS (stride 66) -> 3x3 attn.
__global__ __launch_bounds__(256) void transform_attn_kernel(
    const bf16* __restrict__ prop, const float* __restrict__ rela_k,
    const void* __restrict__ Wgc, int wgc_off, const int* __restrict__ flag,
    bf16* __restrict__ ego_out) {
  bool f32 = *flag != 0;
  __shared__ float est_s[192 * 66];
  int t = threadIdx.x, lane = t & 63, wave = t >> 6;
  int quad = lane >> 4, m = lane & 15;
  int wcol = wave * 16 + m;   // this lane's D column (global 0..63)
  // B fragments (one-time): B[k=quad*8+j][n=wcol]
  short8 b0, b1;
#pragma unroll
  for (int j = 0; j < 8; ++j) {
    int k0 = quad * 8 + j;
    b0[j] = (short)f2bits(loadf(Wgc, wgc_off + k0 * 64 + wcol, f32));
    b1[j] = (short)f2bits(loadf(Wgc, wgc_off + (k0 + 32) * 64 + wcol, f32));
  }
  // rela values at this lane's k positions, for all 3 relations
  float relv0[16], relv1[16], relv2[16];
#pragma unroll
  for (int j = 0; j < 8; ++j) {
    int k0 = quad * 8 + j;
    relv0[j] = rela_k[k0];        relv0[8 + j] = rela_k[32 + k0];
    relv1[j] = rela_k[64 + k0];   relv1[8 + j] = rela_k[96 + k0];
    relv2[j] = rela_k[128 + k0];  relv2[8 + j] = rela_k[160 + k0];
  }
  int n0 = blockIdx.x * 64;
  int row0 = n0 * 3;
#pragma unroll
  for (int tr = 0; tr < 12; ++tr) {
    int rl = tr * 16 + m;            // local A row
    int row = row0 + rl;
    int row_c = row < M3 ? row : 0;
    int i = rl % 3;                  // relation of this row (row0 % 3 == 0)
    const ushort8* pp = (const ushort8*)(prop + (size_t)row_c * 64 + quad * 8);
    ushort8 x0 = pp[0];              // k = quad*8 .. +7
    ushort8 x1 = pp[4];              // k+32
    short8 a0, a1;
#pragma unroll
    for (int j = 0; j < 8; ++j) {
      float r0 = (i == 0) ? relv0[j] : (i == 1 ? relv1[j] : relv2[j]);
      float r1 = (i == 0) ? relv0[8 + j] : (i == 1 ? relv1[8 + j] : relv2[8 + j]);
      a0[j] = (short)f2bits(bits2f(x0[j]) * r0);
      a1[j] = (short)f2bits(bits2f(x1[j]) * r1);
    }
    f32x4 acc = {0.f, 0.f, 0.f, 0.f};
    acc = __builtin_amdgcn_mfma_f32_16x16x32_bf16(a0, b0, acc, 0, 0, 0);
    acc = __builtin_amdgcn_mfma_f32_16x16x32_bf16(a1, b1, acc, 0, 0, 0);
#pragma unroll
    for (int r = 0; r < 4; ++r) {
      float v = acc[r];
      v = v > 0.f ? v : 0.01f * v;   // leaky relu
      est_s[(tr * 16 + quad * 4 + r) * 66 + wcol] = v;
    }
  }
  __syncthreads();
  const float sc = 0.088388347648318447f;  // 1/sqrt(128)
  for (int jj = 0; jj < 16; ++jj) {
    int nl = wave * 16 + jj;
    int n = n0 + nl;
    if (n >= N_NODES) break;
    float e0 = est_s[(3 * nl + 0) * 66 + lane];
    float e1 = est_s[(3 * nl + 1) * 66 + lane];
    float e2 = est_s[(3 * nl + 2) * 66 + lane];
    float s00 = wave_sum(e0 * e0);
    float s01 = wave_sum(e0 * e1);
    float s02 = wave_sum(e0 * e2);
    float s11 = wave_sum(e1 * e1);
    float s12 = wave_sum(e1 * e2);
    float s22 = wave_sum(e2 * e2);
    float o0 = attn_row(s00 * sc, s01 * sc, s02 * sc, e0, e1, e2);
    float o1 = attn_row(s01 * sc, s11 * sc, s12 * sc, e0, e1, e2);
    float o2 = attn_row(s02 * sc, s12 * sc, s22 * sc, e0, e1, e2);
    int base = n * RD + lane;
    ego_out[base] = __float2bfloat16(o0);
    ego_out[base + 64] = __float2bfloat16(o1);
    ego_out[base + 128] = __float2bfloat16(o2);
  }
}

// final: attention row 2, outputs, and MFMA GRU + scores.
// Block = 64 nodes. fmat row = i*64 + node_local, stride 66.
__global__ __launch_bounds__(256) void final_kernel(
    const bf16* __restrict__ ego0, const bf16* __restrict__ ego1,
    const bf16* __restrict__ ego2, const void* __restrict__ gru_w,
    const void* __restrict__ gru_b, const void* __restrict__ tra,
    const int* __restrict__ flag, void* out) {
  bool f32 = *flag != 0;
  __shared__ float fmat[192 * 66];
  __shared__ float sc_lds[128];   // [64 nodes][2]
  int t = threadIdx.x, lane = t & 63, wave = t >> 6;
  int quad = lane >> 4, m = lane & 15;
  int wcol = wave * 16 + m;
  if (t < 128) sc_lds[t] = 0.f;
  // B-frags for gru_w[0..2]; biases; tra scalars (per-lane)
  short8 bw[3][2];
#pragma unroll
  for (int i = 0; i < 3; ++i)
#pragma unroll
    for (int j = 0; j < 8; ++j) {
      int k0 = quad * 8 + j;
      bw[i][0][j] = (short)f2bits(loadf(gru_w, i * 4096 + k0 * 64 + wcol, f32));
      bw[i][1][j] =
          (short)f2bits(loadf(gru_w, i * 4096 + (k0 + 32) * 64 + wcol, f32));
    }
  float bias0 = loadf(gru_b, wcol, f32);
  float bias1 = loadf(gru_b, 64 + wcol, f32);
  float bias2 = loadf(gru_b, 128 + wcol, f32);
  float ts0 = loadf(tra, wcol, f32);        // tra[0][:64]   (tgt -> sc1)
  float ts1 = loadf(tra, 64 + wcol, f32);   // tra[0][64:]   (aux1 -> sc1)
  float ts2 = loadf(tra, 128 + wcol, f32);  // tra[1][:64]   (tgt -> sc2)
  float ts3 = loadf(tra, 192 + wcol, f32);  // tra[1][64:]   (aux2 -> sc2)

  int n0 = blockIdx.x * 64;
  // Phase 1: attention + u/i outputs + fmat
  for (int jj = 0; jj < 16; ++jj) {
    int nl = wave * 16 + jj;
    int n = n0 + nl;
    float f0 = 0.f, f1 = 0.f, f2 = 0.f;
    if (n < N_NODES) {
      int b0i = n * RD + lane;
      float a0 = b2f(ego0[b0i]) + b2f(ego1[b0i]) + b2f(ego2[b0i]);
      float a1 =
          b2f(ego0[b0i + 64]) + b2f(ego1[b0i + 64]) + b2f(ego2[b0i + 64]);
      float a2 =
          b2f(ego0[b0i + 128]) + b2f(ego1[b0i + 128]) + b2f(ego2[b0i + 128]);
      float s20 = wave_sum(a2 * a0);
      float s21 = wave_sum(a2 * a1);
      float s22 = wave_sum(a2 * a2);
      float mid2 = attn_row(s20, s21, s22, a0, a1, a2);
      f0 = a0 * (1.f / 3.f);
      f1 = a1 * (1.f / 3.f);
      f2 = mid2 * (1.f / 3.f);
      if (n < N_USERS) {
        int ob = OFF_U + n * RD + lane;
        storef(out, ob, f0, f32);
        storef(out, ob + 64, f1, f32);
        storef(out, ob + 128, f2, f32);
      } else {
        int ob = OFF_I + (n - N_USERS) * RD + lane;
        storef(out, ob, f0, f32);
        storef(out, ob + 64, f1, f32);
        storef(out, ob + 128, f2, f32);
      }
    }
    fmat[(0 * 64 + nl) * 66 + lane] = f0;
    fmat[(1 * 64 + nl) * 66 + lane] = f1;
    fmat[(2 * 64 + nl) * 66 + lane] = f2;
  }
  __syncthreads();
  // Phase 2: 3 GEMMs (64x64 @ 64x64) + score partials
#pragma unroll
  for (int i = 0; i < 3; ++i) {
    float bias = (i == 0) ? bias0 : (i == 1 ? bias1 : bias2);
#pragma unroll
    for (int tr = 0; tr < 4; ++tr) {
      int arow = (i * 64 + tr * 16 + m) * 66;
      short8 a0, a1;
#pragma unroll
      for (int j = 0; j < 8; ++j) {
        a0[j] = (short)f2bits(fmat[arow + quad * 8 + j]);
        a1[j] = (short)f2bits(fmat[arow + quad * 8 + j + 32]);
      }
      f32x4 acc = {0.f, 0.f, 0.f, 0.f};
      acc = __builtin_amdgcn_mfma_f32_16x16x32_bf16(a0, bw[i][0], acc, 0, 0, 0);
      acc = __builtin_amdgcn_mfma_f32_16x16x32_bf16(a1, bw[i][1], acc, 0, 0, 0);
#pragma unroll
      for (int r = 0; r < 4; ++r) {
        int nl = tr * 16 + quad * 4 + r;
        float y = acc[r] + bias;
        float f = fmat[(i * 64 + nl) * 66 + wcol];
        float prod = f * y;
        float p1 = 0.f, p2 = 0.f;
        if (i == 0) p1 = prod * ts1;
        else if (i == 1) p2 = prod * ts3;
        else { p1 = prod * ts0; p2 = prod * ts2; }
        // reduce over 16 cols (m-lanes, stays within quad)
#pragma unroll
        for (int off = 1; off < 16; off <<= 1) {
          p1 += __shfl_xor(p1, off, 64);
          p2 += __shfl_xor(p2, off, 64);
        }
        if (m == 0) {
          if (i != 1) atomicAdd(&sc_lds[nl * 2], p1);
          if (i != 0) atomicAdd(&sc_lds[nl * 2 + 1], p2);
        }
      }
    }
  }
  __syncthreads();
  // Phase 3: score outputs
  if (t < 64) {
    int n = n0 + t;
    if (n < N_USERS) {
      storef(out, OFF_S1 + n, sc_lds[t * 2], f32);
      storef(out, OFF_S2 + n, sc_lds[t * 2 + 1], f32);
    }
  }
}

extern "C" void kernel_launch(void* const* d_in, const int* in_sizes, int n_in,
                              void* d_out, int out_size, void* d_ws,
                              size_t ws_size, hipStream_t stream) {
  const void* user_emb = d_in[0];
  const void* item_emb = d_in[1];
  const void* rel_emb = d_in[2];
  const void* W_gc = d_in[3];
  const void* W_rel = d_in[4];
  const void* gru_w = d_in[5];
  const void* gru_b = d_in[6];
  const void* tra = d_in[7];
  const void* adj_vals = d_in[8];
  const int* adj_rows = (const int*)d_in[9];
  const int* adj_cols = (const int*)d_in[10];

  // ws layout (~156 MB)
  int* flag = (int*)d_ws;
  float* wsf = (float*)d_ws;
  float* rela_f = wsf + 16;                       // 576 floats
  int* counts = (int*)(wsf + 1024);               // 300k
  int* offs = counts + M3;                        // 300k
  int* gcursor = offs + M3;                       // 512
  int* bcnt = gcursor + 512;                      // 512
  int* bbase = bcnt + 512;                        // 512
  u64* abuf = (u64*)(bbase + 512);                // 4.8M u64 (8B-aligned)
  int2* sedge = (int2*)(abuf + NE3);              // 4.8M int2
  bf16* ego0 = (bf16*)(sedge + NE3);              // 19.2M bf16
  bf16* ego1 = ego0 + (size_t)N_NODES * RD;
  bf16* ego2 = ego1 + (size_t)N_NODES * RD;
  bf16* prop = ego2 + (size_t)N_NODES * RD;

  const int nbE = (NE3 + 4095) / 4096;            // 1172

  detect_kernel<<<1, 256, 0, stream>>>((const unsigned short*)user_emb, flag);
  rela_kernel<<<1, 192, 0, stream>>>(rel_emb, W_rel, flag, rela_f, d_out);
  zero_row_kernel<<<1, 192, 0, stream>>>(d_out, flag);
  init_kernel<<<(N_NODES * RD / 4 + 255) / 256, 256, 0, stream>>>(
      user_emb, item_emb, flag, ego0);

  (void)hipMemsetAsync(bcnt, 0, 512 * sizeof(int), stream);
  bhist_kernel<<<nbE, 256, 0, stream>>>(adj_rows, bcnt);
  bscan_kernel<<<1, 512, 0, stream>>>(bcnt, gcursor, bbase);
  passA_kernel<<<nbE, 256, 0, stream>>>(
      adj_rows, adj_cols, adj_vals, flag, gcursor, abuf);
  passB_kernel<<<NBUCK, 256, 0, stream>>>(abuf, bbase, bcnt, offs, counts,
                                          sedge);

  gather_kernel<<<M3 / 4, 256, 0, stream>>>(sedge, counts, offs, ego0, prop);
  transform_attn_kernel<<<(N_NODES + 63) / 64, 256, 0, stream>>>(
      prop, rela_f, W_gc, 0, flag, ego1);
  gather_kernel<<<M3 / 4, 256, 0, stream>>>(sedge, counts, offs, ego1, prop);
  transform_attn_kernel<<<(N_NODES + 63) / 64, 256, 0, stream>>>(
      prop, rela_f + 192, W_gc, 4096, flag, ego2);

  final_kernel<<<(N_NODES + 63) / 64, 256, 0, stream>>>(
      ego0, ego1, ego2, gru_w, gru_b, tra, flag, d_out);
}

// Round 3
// 778.112 us; speedup vs baseline: 1.5176x; 1.0786x over previous
//
#include <hip/hip_runtime.h>
#include <hip/hip_bf16.h>

#define N_USERS 70000
#define N_ITEMS 30000
#define N_NODES 100000
#define RD 192      // R*D
#define EE 1600000
#define NE3 4800000
#define M3 300000   // 3 * N_NODES segments
#define NSUB 98     // ceil(100000/1024) row sub-buckets
#define NBUCK 294   // 3 * NSUB

// output element offsets (dtype-independent)
#define OFF_U    0
#define OFF_I    13440000
#define OFF_IZ   19200000   // zero row (item index 30000)
#define OFF_RELA 19200192
#define OFF_S1   19200384
#define OFF_S2   19270384

typedef __hip_bfloat16 bf16;
typedef unsigned long long u64;
typedef __attribute__((ext_vector_type(8))) short short8;
typedef __attribute__((ext_vector_type(8))) unsigned short ushort8;
typedef __attribute__((ext_vector_type(4))) float f32x4;

__device__ __forceinline__ float b2f(bf16 v) { return __bfloat162float(v); }

union bfbits { bf16 b; unsigned short u; };

__device__ __forceinline__ float bits2f(unsigned short u) {
  bfbits x; x.u = u; return b2f(x.b);
}
__device__ __forceinline__ unsigned short f2bits(float f) {
  bfbits x; x.b = __float2bfloat16(f); return x.u;
}

// dtype-adaptive IO: f32 -> fp32 arrays, else bf16 arrays
__device__ __forceinline__ float loadf(const void* p, int i, bool f32) {
  return f32 ? ((const float*)p)[i] : b2f(((const bf16*)p)[i]);
}
__device__ __forceinline__ void storef(void* p, int i, float v, bool f32) {
  if (f32) ((float*)p)[i] = v;
  else ((bf16*)p)[i] = __float2bfloat16(v);
}

__device__ __forceinline__ float wave_sum(float v) {
#pragma unroll
  for (int off = 32; off >= 1; off >>= 1) v += __shfl_xor(v, off, 64);
  return v;
}

__global__ void detect_kernel(const unsigned short* __restrict__ ue,
                              int* __restrict__ flag) {
  __shared__ int s;
  int t = threadIdx.x;
  if (t == 0) s = 0;
  __syncthreads();
  int big = 0;
  for (int j = t; j < 8192; j += 256) {
    int e = (ue[j] >> 7) & 0xFF;
    if (e >= 127) big = 1;
  }
  if (big) atomicOr(&s, 1);
  __syncthreads();
  if (t == 0) *flag = s;
}

__global__ void zero_row_kernel(void* out, const int* __restrict__ flag) {
  bool f32 = *flag != 0;
  storef(out, OFF_IZ + (int)threadIdx.x, 0.f, f32);  // 192 threads
}

// rela chain: rela0=rel_emb, rela1=rela0@W_rel[0], rela2=rela1@W_rel[1]
__global__ void rela_kernel(const void* __restrict__ rel_emb,
                            const void* __restrict__ W_rel,
                            const int* __restrict__ flag,
                            float* __restrict__ rela_f, void* out) {
  bool f32 = *flag != 0;
  __shared__ float r0s[192], r1s[192];
  int t = threadIdx.x;            // 192 threads
  int i = t >> 6, d = t & 63;
  float r0 = loadf(rel_emb, t, f32);
  r0s[t] = r0;
  __syncthreads();
  float acc = 0.f;
  for (int k = 0; k < 64; ++k)
    acc += r0s[i * 64 + k] * loadf(W_rel, k * 64 + d, f32);
  r1s[t] = acc;
  __syncthreads();
  float acc2 = 0.f;
  for (int k = 0; k < 64; ++k)
    acc2 += r1s[i * 64 + k] * loadf(W_rel, 4096 + k * 64 + d, f32);
  rela_f[t] = r0;
  rela_f[192 + t] = acc;
  rela_f[384 + t] = acc2;
  storef(out, OFF_RELA + t, (r0 + acc + acc2) * (1.f / 3.f), f32);
}

// vectorized x4: one thread converts 4 contiguous dims (never crosses 64-dim
// boundary since 4 | 64)
__global__ __launch_bounds__(256) void init_kernel(
    const void* __restrict__ user_emb, const void* __restrict__ item_emb,
    const int* __restrict__ flag, bf16* __restrict__ ego0) {
  bool f32 = *flag != 0;
  int idx4 = blockIdx.x * 256 + threadIdx.x;
  if (idx4 >= N_NODES * RD / 4) return;
  int idx = idx4 << 2;
  int n = idx / RD;
  int rd = idx - n * RD;
  int d = rd & 63;
  const void* src;
  int off;
  if (n < N_USERS) { src = user_emb; off = n * 64 + d; }
  else             { src = item_emb; off = (n - N_USERS) * 64 + d; }
  ushort4 o;
  if (f32) {
    float4 fv = *(const float4*)((const float*)src + off);
    o.x = f2bits(fv.x); o.y = f2bits(fv.y); o.z = f2bits(fv.z); o.w = f2bits(fv.w);
  } else {
    o = *(const ushort4*)((const unsigned short*)src + off);
  }
  *(ushort4*)(ego0 + idx) = o;
}

// ---- CSR build (hierarchical; no 300K global-atomic histogram) ----
// Stage 1: per-block LDS histogram of the 294 (rel, row>>10) buckets.
__global__ __launch_bounds__(256) void bhist_kernel(
    const int* __restrict__ rows, int* __restrict__ bcnt) {
  __shared__ int h[NBUCK];
  int t = threadIdx.x;
  for (int j = t; j < NBUCK; j += 256) h[j] = 0;
  __syncthreads();
  int base = blockIdx.x * 4096;
  int m = min(4096, NE3 - base);
  for (int j = t; j < m; j += 256) {
    int idx = base + j;
    int i = idx / EE;
    int r = rows[idx];
    atomicAdd(&h[i * NSUB + (r >> 10)], 1);
  }
  __syncthreads();
  for (int j = t; j < NBUCK; j += 256)
    if (h[j]) atomicAdd(&bcnt[j], h[j]);
}

// Stage 2: exclusive scan of 294 bucket counts -> bucket bases.
// Writes both gcursor (mutated by passA) and bbase (read by passB).
__global__ __launch_bounds__(512) void bscan_kernel(
    const int* __restrict__ bcnt, int* __restrict__ gcursor,
    int* __restrict__ bbase) {
  __shared__ int s[512];
  int t = threadIdx.x;
  int x = (t < NBUCK) ? bcnt[t] : 0;
  s[t] = x;
  __syncthreads();
  for (int off = 1; off < 512; off <<= 1) {
    int y = (t >= off) ? s[t - off] : 0;
    __syncthreads();
    s[t] += y;
    __syncthreads();
  }
  if (t < NBUCK) {
    int e = s[t] - x;
    gcursor[t] = e;
    bbase[t] = e;
  }
}

// Pass A: bucket edges into 294 (rel, row>>10) buckets; runs are
// block-contiguous -> L2 coalesces lines. Packed u64: rowlo<<48|col<<16|bf16
__global__ __launch_bounds__(256) void passA_kernel(
    const int* __restrict__ rows, const int* __restrict__ cols,
    const void* __restrict__ vals, const int* __restrict__ flag,
    int* __restrict__ gcursor, u64* __restrict__ abuf) {
  bool f32 = *flag != 0;
  __shared__ u64 pk[4096];
  __shared__ unsigned short bk[4096];
  __shared__ int cnt[NBUCK], pos[NBUCK], gbase[NBUCK];
  int t = threadIdx.x;
  for (int j = t; j < NBUCK; j += 256) { cnt[j] = 0; pos[j] = 0; }
  __syncthreads();
  int base = blockIdx.x * 4096;
  int m = min(4096, NE3 - base);
  for (int j = t; j < m; j += 256) {
    int idx = base + j;
    int i = idx / EE;
    int r = rows[idx];
    int c = cols[idx];
    unsigned short vb =
        f32 ? f2bits(((const float*)vals)[idx])
            : ((const unsigned short*)vals)[idx];
    int sub = r >> 10;
    int b = i * NSUB + sub;
    pk[j] = ((u64)(r & 1023) << 48) | ((u64)(unsigned)c << 16) | vb;
    bk[j] = (unsigned short)b;
    atomicAdd(&cnt[b], 1);
  }
  __syncthreads();
  for (int j = t; j < NBUCK; j += 256)
    if (cnt[j] > 0) gbase[j] = atomicAdd(&gcursor[j], cnt[j]);
  __syncthreads();
  for (int j = t; j < m; j += 256) {
    int b = bk[j];
    int p = atomicAdd(&pos[b], 1);
    abuf[gbase[b] + p] = pk[j];
  }
}

// Pass B: one block per bucket. Builds the within-bucket row CSR in LDS
// (1024-bin histogram + scan over the bucket's edges), writes offs/counts
// for its contiguous segment range, then scatters edges to sedge.
// sedge payload: .x = precomputed ego BYTE offset (col*384 + rel*128),
//                .y = f32 edge weight bits
__global__ __launch_bounds__(256) void passB_kernel(
    const u64* __restrict__ abuf, const int* __restrict__ bbase,
    const int* __restrict__ bcnt, int* __restrict__ offs,
    int* __restrict__ counts, int2* __restrict__ sedge) {
  __shared__ int hist[1024];   // per-row counts, then global cursors
  __shared__ int s[256];
  int b = blockIdx.x;
  int rel = b / NSUB, sub = b - rel * NSUB;
  int r0 = sub << 10;
  int nr = min(1024, N_NODES - r0);   // 1024 or 672; always %4==0
  int gi = rel * N_NODES + r0;
  int t = threadIdx.x;
  for (int j = t; j < 1024; j += 256) hist[j] = 0;
  __syncthreads();
  int start = bbase[b];
  int cnt = bcnt[b];
  int end = start + cnt;
  for (int e = start + t; e < end; e += 256)
    atomicAdd(&hist[(int)(abuf[e] >> 48)], 1);
  __syncthreads();
  // exclusive scan over 1024 bins: 4 sequential per thread + 256-wide scan
  int j0 = t << 2;
  int a0 = hist[j0], a1 = hist[j0 + 1], a2 = hist[j0 + 2], a3 = hist[j0 + 3];
  int lsum = a0 + a1 + a2 + a3;
  s[t] = lsum;
  __syncthreads();
  for (int off = 1; off < 256; off <<= 1) {
    int y = (t >= off) ? s[t - off] : 0;
    __syncthreads();
    s[t] += y;
    __syncthreads();
  }
  int o0 = start + s[t] - lsum;
  int o1 = o0 + a0, o2 = o1 + a1, o3 = o2 + a2;
  // all hist reads completed before the scan barriers -> safe to overwrite
  hist[j0] = o0; hist[j0 + 1] = o1; hist[j0 + 2] = o2; hist[j0 + 3] = o3;
  if (j0 < nr) {
    *(int4*)(offs + gi + j0) = make_int4(o0, o1, o2, o3);
    *(int4*)(counts + gi + j0) = make_int4(a0, a1, a2, a3);
  }
  __syncthreads();
  int rbase = rel * 128;
  for (int e = start + t; e < end; e += 256) {
    u64 w = abuf[e];
    int rowlo = (int)(w >> 48);
    int c = (int)((w >> 16) & 0x3FFFF);
    float v = bits2f((unsigned short)(w & 0xFFFF));
    int p = atomicAdd(&hist[rowlo], 1);
    int2 eo; eo.x = c * 384 + rbase; eo.y = __float_as_int(v);
    sedge[p] = eo;
  }
}

// one wave per (node, relation) segment. Pair-packed loads: lanes 0-31 fetch
// even edge's 128B ego line, lanes 32-63 the odd edge's line; each lane loads
// one dword (2 bf16 dims). 8 pair-instructions per batch = 16 lines in flight
// per wave. Edge headers carry precomputed byte offsets + f32 weight, so the
// inner loop is ~4 VALU/edge. Halves combined with one shfl_xor(32).
__global__ __launch_bounds__(256, 8) void gather_kernel(
    const int2* __restrict__ sedge, const int* __restrict__ counts,
    const int* __restrict__ offs, const bf16* __restrict__ ego,
    bf16* __restrict__ prop) {
  int seg = blockIdx.x * 4 + (threadIdx.x >> 6);   // i*N_NODES + n
  int lane = threadIdx.x & 63;
  int half = lane >> 5;        // 0: even edge of pair, 1: odd edge
  int k = lane & 31;           // dim-pair index: dims 2k, 2k+1
  int voff = k << 2;           // byte offset within the 128B line
  int i = seg / N_NODES;
  int n = seg - i * N_NODES;
  int base = offs[seg];
  int cnt = counts[seg];
  const char* egob = (const char*)ego;
  float acc0 = 0.f, acc1 = 0.f;
  int j = 0;
  for (; j + 16 <= cnt; j += 16) {
    int2 h[8];
    unsigned d[8];
#pragma unroll
    for (int u = 0; u < 8; ++u) h[u] = sedge[base + j + 2 * u + half];
#pragma unroll
    for (int u = 0; u < 8; ++u)
      d[u] = *(const unsigned*)(egob + (size_t)((unsigned)h[u].x + voff));
#pragma unroll
    for (int u = 0; u < 8; ++u) {
      float vv = __int_as_float(h[u].y);
      acc0 = fmaf(__int_as_float(d[u] << 16), vv, acc0);
      acc1 = fmaf(__int_as_float(d[u] & 0xffff0000u), vv, acc1);
    }
  }
  // tail: up to 15 edges as one masked parallel batch (np pairs, wave-uniform)
  int rem = cnt - j;
  if (rem > 0) {
    int np = (rem + 1) >> 1;   // 1..8
    int2 h[8];
    unsigned d[8];
#pragma unroll
    for (int u = 0; u < 8; ++u)
      if (u < np) {
        int idx = 2 * u + half;
        h[u] = sedge[base + j + (idx < rem ? idx : rem - 1)];
      }
#pragma unroll
    for (int u = 0; u < 8; ++u)
      if (u < np)
        d[u] = *(const unsigned*)(egob + (size_t)((unsigned)h[u].x + voff));
#pragma unroll
    for (int u = 0; u < 8; ++u)
      if (u < np) {
        float vv = (2 * u + half < rem) ? __int_as_float(h[u].y) : 0.f;
        acc0 = fmaf(__int_as_float(d[u] << 16), vv, acc0);
        acc1 = fmaf(__int_as_float(d[u] & 0xffff0000u), vv, acc1);
      }
  }
  acc0 += __shfl_xor(acc0, 32, 64);
  acc1 += __shfl_xor(acc1, 32, 64);
  if (half == 0) {
    unsigned lo = f2bits(acc0);
    unsigned hi = f2bits(acc1);
    *(unsigned*)((char*)prop + (size_t)(n * RD + i * 64) * 2 + voff) =
        lo | (hi << 16);
  }
}

__device__ __forceinline__ float attn_row(float a, float b, float c,
                                          float e0, float e1, float e2) {
  float m = fmaxf(a, fmaxf(b, c));
  float w0 = __expf(a - m), w1 = __expf(b - m), w2 = __expf(c - m);
  float inv = 1.f / (w0 + w1 + w2);
  return (w0 * e0 + w1 * e1 + w2 * e2) * inv;
}

// MFMA transform: X(300000x64) @ W(64x64), X = prop * rela (per-relation).
// Block = 64 nodes = 192 X-rows. Wave w owns W cols [16w,16w+16).
// 12 row-tiles x 2 mfma_16x16x32_bf16.
// est stored bf16 TRANSPOSED: est_t[col][row], stride 198 (odd-dword ->
// Gram reads land 2 lanes/bank = conflict-free). LDS 25.3KB (was 50.7KB f32)
// -> ~2x occupancy. MFMA results packed as 2x u32 stores (4 rows/lane).
__global__ __launch_bounds__(256, 4) void transform_attn_kernel(
    const bf16* __restrict__ prop, const float* __restrict__ rela_k,
    const void* __restrict__ Wgc, int wgc_off, const int* __restrict__ flag,
    bf16* __restrict__ ego_out) {
  bool f32 = *flag != 0;
  __shared__ __align__(16) unsigned short est_t[64 * 198];
  int t = threadIdx.x, lane = t & 63, wave = t >> 6;
  int quad = lane >> 4, m = lane & 15;
  int wcol = wave * 16 + m;   // this lane's D column (global 0..63)
  // B fragments (one-time): B[k=quad*8+j][n=wcol]
  short8 b0, b1;
#pragma unroll
  for (int j = 0; j < 8; ++j) {
    int k0 = quad * 8 + j;
    b0[j] = (short)f2bits(loadf(Wgc, wgc_off + k0 * 64 + wcol, f32));
    b1[j] = (short)f2bits(loadf(Wgc, wgc_off + (k0 + 32) * 64 + wcol, f32));
  }
  // rela values at this lane's k positions, for all 3 relations
  float relv0[16], relv1[16], relv2[16];
#pragma unroll
  for (int j = 0; j < 8; ++j) {
    int k0 = quad * 8 + j;
    relv0[j] = rela_k[k0];        relv0[8 + j] = rela_k[32 + k0];
    relv1[j] = rela_k[64 + k0];   relv1[8 + j] = rela_k[96 + k0];
    relv2[j] = rela_k[128 + k0];  relv2[8 + j] = rela_k[160 + k0];
  }
  int n0 = blockIdx.x * 64;
  int row0 = n0 * 3;
#pragma unroll
  for (int tr = 0; tr < 12; ++tr) {
    int rl = tr * 16 + m;            // local A row
    int row = row0 + rl;
    int row_c = row < M3 ? row : 0;
    int i = rl % 3;                  // relation of this row (row0 % 3 == 0)
    const ushort8* pp = (const ushort8*)(prop + (size_t)row_c * 64 + quad * 8);
    ushort8 x0 = pp[0];              // k = quad*8 .. +7
    ushort8 x1 = pp[4];              // k+32
    short8 a0, a1;
#pragma unroll
    for (int j = 0; j < 8; ++j) {
      float r0 = (i == 0) ? relv0[j] : (i == 1 ? relv1[j] : relv2[j]);
      float r1 = (i == 0) ? relv0[8 + j] : (i == 1 ? relv1[8 + j] : relv2[8 + j]);
      a0[j] = (short)f2bits(bits2f(x0[j]) * r0);
      a1[j] = (short)f2bits(bits2f(x1[j]) * r1);
    }
    f32x4 acc = {0.f, 0.f, 0.f, 0.f};
    acc = __builtin_amdgcn_mfma_f32_16x16x32_bf16(a0, b0, acc, 0, 0, 0);
    acc = __builtin_amdgcn_mfma_f32_16x16x32_bf16(a1, b1, acc, 0, 0, 0);
    float v0 = acc[0]; v0 = v0 > 0.f ? v0 : 0.01f * v0;
    float v1 = acc[1]; v1 = v1 > 0.f ? v1 : 0.01f * v1;
    float v2 = acc[2]; v2 = v2 > 0.f ? v2 : 0.01f * v2;
    float v3 = acc[3]; v3 = v3 > 0.f ? v3 : 0.01f * v3;
    unsigned w0 = (unsigned)f2bits(v0) | ((unsigned)f2bits(v1) << 16);
    unsigned w1 = (unsigned)f2bits(v2) | ((unsigned)f2bits(v3) << 16);
    unsigned* p32 = (unsigned*)(est_t + wcol * 198 + tr * 16 + quad * 4);
    p32[0] = w0; p32[1] = w1;
  }
  __syncthreads();
  const float sc = 0.088388347648318447f;  // 1/sqrt(128)
  for (int jj = 0; jj < 16; ++jj) {
    int nl = wave * 16 + jj;
    int n = n0 + nl;
    if (n >= N_NODES) break;
    int rb = lane * 198 + 3 * nl;
    float e0 = bits2f(est_t[rb]);
    float e1 = bits2f(est_t[rb + 1]);
    float e2 = bits2f(est_t[rb + 2]);
    float s00 = wave_sum(e0 * e0);
    float s01 = wave_sum(e0 * e1);
    float s02 = wave_sum(e0 * e2);
    float s11 = wave_sum(e1 * e1);
    float s12 = wave_sum(e1 * e2);
    float s22 = wave_sum(e2 * e2);
    float o0 = attn_row(s00 * sc, s01 * sc, s02 * sc, e0, e1, e2);
    float o1 = attn_row(s01 * sc, s11 * sc, s12 * sc, e0, e1, e2);
    float o2 = attn_row(s02 * sc, s12 * sc, s22 * sc, e0, e1, e2);
    int base = n * RD + lane;
    ego_out[base] = __float2bfloat16(o0);
    ego_out[base + 64] = __float2bfloat16(o1);
    ego_out[base + 128] = __float2bfloat16(o2);
  }
}

// final: attention row 2, outputs, and MFMA GRU + scores.
// fmat stored bf16, row stride 72 (16B-aligned rows): LDS 28KB (was 51KB)
// -> 2x+ occupancy. Phase-2 A-frags via 2x ds_read_b128 (no conversion).
// Score partials accumulated over i in registers; single reduce per (tr,r).
__global__ __launch_bounds__(256, 4) void final_kernel(
    const bf16* __restrict__ ego0, const bf16* __restrict__ ego1,
    const bf16* __restrict__ ego2, const void* __restrict__ gru_w,
    const void* __restrict__ gru_b, const void* __restrict__ tra,
    const int* __restrict__ flag, void* out) {
  bool f32 = *flag != 0;
  __shared__ __align__(16) unsigned short fmatu[192 * 72];
  __shared__ float sc_lds[128];   // [64 nodes][2]
  int t = threadIdx.x, lane = t & 63, wave = t >> 6;
  int quad = lane >> 4, m = lane & 15;
  int wcol = wave * 16 + m;
  if (t < 128) sc_lds[t] = 0.f;
  // B-frags for gru_w[0..2]; biases; tra scalars (per-lane)
  short8 bw[3][2];
#pragma unroll
  for (int i = 0; i < 3; ++i)
#pragma unroll
    for (int j = 0; j < 8; ++j) {
      int k0 = quad * 8 + j;
      bw[i][0][j] = (short)f2bits(loadf(gru_w, i * 4096 + k0 * 64 + wcol, f32));
      bw[i][1][j] =
          (short)f2bits(loadf(gru_w, i * 4096 + (k0 + 32) * 64 + wcol, f32));
    }
  float bias0 = loadf(gru_b, wcol, f32);
  float bias1 = loadf(gru_b, 64 + wcol, f32);
  float bias2 = loadf(gru_b, 128 + wcol, f32);
  float ts0 = loadf(tra, wcol, f32);        // tra[0][:64]   (tgt -> sc1)
  float ts1 = loadf(tra, 64 + wcol, f32);   // tra[0][64:]   (aux1 -> sc1)
  float ts2 = loadf(tra, 128 + wcol, f32);  // tra[1][:64]   (tgt -> sc2)
  float ts3 = loadf(tra, 192 + wcol, f32);  // tra[1][64:]   (aux2 -> sc2)

  int n0 = blockIdx.x * 64;
  // Phase 1: attention + u/i outputs + fmat
  for (int jj = 0; jj < 16; ++jj) {
    int nl = wave * 16 + jj;
    int n = n0 + nl;
    float f0 = 0.f, f1 = 0.f, f2 = 0.f;
    if (n < N_NODES) {
      int b0i = n * RD + lane;
      float a0 = b2f(ego0[b0i]) + b2f(ego1[b0i]) + b2f(ego2[b0i]);
      float a1 =
          b2f(ego0[b0i + 64]) + b2f(ego1[b0i + 64]) + b2f(ego2[b0i + 64]);
      float a2 =
          b2f(ego0[b0i + 128]) + b2f(ego1[b0i + 128]) + b2f(ego2[b0i + 128]);
      float s20 = wave_sum(a2 * a0);
      float s21 = wave_sum(a2 * a1);
      float s22 = wave_sum(a2 * a2);
      float mid2 = attn_row(s20, s21, s22, a0, a1, a2);
      f0 = a0 * (1.f / 3.f);
      f1 = a1 * (1.f / 3.f);
      f2 = mid2 * (1.f / 3.f);
      if (n < N_USERS) {
        int ob = OFF_U + n * RD + lane;
        storef(out, ob, f0, f32);
        storef(out, ob + 64, f1, f32);
        storef(out, ob + 128, f2, f32);
      } else {
        int ob = OFF_I + (n - N_USERS) * RD + lane;
        storef(out, ob, f0, f32);
        storef(out, ob + 64, f1, f32);
        storef(out, ob + 128, f2, f32);
      }
    }
    fmatu[(0 * 64 + nl) * 72 + lane] = f2bits(f0);
    fmatu[(1 * 64 + nl) * 72 + lane] = f2bits(f1);
    fmatu[(2 * 64 + nl) * 72 + lane] = f2bits(f2);
  }
  __syncthreads();
  // Phase 2: 3 GEMMs (64x64 @ 64x64); score partials accumulated over i
  float p1a[4][4], p2a[4][4];
#pragma unroll
  for (int tr = 0; tr < 4; ++tr)
#pragma unroll
    for (int r = 0; r < 4; ++r) { p1a[tr][r] = 0.f; p2a[tr][r] = 0.f; }
#pragma unroll
  for (int i = 0; i < 3; ++i) {
    float bias = (i == 0) ? bias0 : (i == 1 ? bias1 : bias2);
#pragma unroll
    for (int tr = 0; tr < 4; ++tr) {
      int arow = (i * 64 + tr * 16 + m) * 72;
      short8 a0 = *(const short8*)(fmatu + arow + quad * 8);
      short8 a1 = *(const short8*)(fmatu + arow + 32 + quad * 8);
      f32x4 acc = {0.f, 0.f, 0.f, 0.f};
      acc = __builtin_amdgcn_mfma_f32_16x16x32_bf16(a0, bw[i][0], acc, 0, 0, 0);
      acc = __builtin_amdgcn_mfma_f32_16x16x32_bf16(a1, bw[i][1], acc, 0, 0, 0);
#pragma unroll
      for (int r = 0; r < 4; ++r) {
        int nl = tr * 16 + quad * 4 + r;
        float y = acc[r] + bias;
        float f = bits2f(fmatu[(i * 64 + nl) * 72 + wcol]);
        float prod = f * y;
        if (i == 0) p1a[tr][r] += prod * ts1;
        else if (i == 1) p2a[tr][r] += prod * ts3;
        else { p1a[tr][r] += prod * ts0; p2a[tr][r] += prod * ts2; }
      }
    }
  }
  // single reduce per (tr,r) over the 16 m-lanes, then LDS accumulate
#pragma unroll
  for (int tr = 0; tr < 4; ++tr)
#pragma unroll
    for (int r = 0; r < 4; ++r) {
      float p1 = p1a[tr][r], p2 = p2a[tr][r];
#pragma unroll
      for (int off = 1; off < 16; off <<= 1) {
        p1 += __shfl_xor(p1, off, 64);
        p2 += __shfl_xor(p2, off, 64);
      }
      if (m == 0) {
        int nl = tr * 16 + quad * 4 + r;
        atomicAdd(&sc_lds[nl * 2], p1);
        atomicAdd(&sc_lds[nl * 2 + 1], p2);
      }
    }
  __syncthreads();
  // Phase 3: score outputs
  if (t < 64) {
    int n = n0 + t;
    if (n < N_USERS) {
      storef(out, OFF_S1 + n, sc_lds[t * 2], f32);
      storef(out, OFF_S2 + n, sc_lds[t * 2 + 1], f32);
    }
  }
}

extern "C" void kernel_launch(void* const* d_in, const int* in_sizes, int n_in,
                              void* d_out, int out_size, void* d_ws,
                              size_t ws_size, hipStream_t stream) {
  const void* user_emb = d_in[0];
  const void* item_emb = d_in[1];
  const void* rel_emb = d_in[2];
  const void* W_gc = d_in[3];
  const void* W_rel = d_in[4];
  const void* gru_w = d_in[5];
  const void* gru_b = d_in[6];
  const void* tra = d_in[7];
  const void* adj_vals = d_in[8];
  const int* adj_rows = (const int*)d_in[9];
  const int* adj_cols = (const int*)d_in[10];

  // ws layout (~156 MB)
  int* flag = (int*)d_ws;
  float* wsf = (float*)d_ws;
  float* rela_f = wsf + 16;                       // 576 floats
  int* counts = (int*)(wsf + 1024);               // 300k
  int* offs = counts + M3;                        // 300k
  int* gcursor = offs + M3;                       // 512
  int* bcnt = gcursor + 512;                      // 512
  int* bbase = bcnt + 512;                        // 512
  u64* abuf = (u64*)(bbase + 512);                // 4.8M u64 (8B-aligned)
  int2* sedge = (int2*)(abuf + NE3);              // 4.8M int2
  bf16* ego0 = (bf16*)(sedge + NE3);              // 19.2M bf16
  bf16* ego1 = ego0 + (size_t)N_NODES * RD;
  bf16* ego2 = ego1 + (size_t)N_NODES * RD;
  bf16* prop = ego2 + (size_t)N_NODES * RD;

  const int nbE = (NE3 + 4095) / 4096;            // 1172

  detect_kernel<<<1, 256, 0, stream>>>((const unsigned short*)user_emb, flag);
  rela_kernel<<<1, 192, 0, stream>>>(rel_emb, W_rel, flag, rela_f, d_out);
  zero_row_kernel<<<1, 192, 0, stream>>>(d_out, flag);
  init_kernel<<<(N_NODES * RD / 4 + 255) / 256, 256, 0, stream>>>(
      user_emb, item_emb, flag, ego0);

  (void)hipMemsetAsync(bcnt, 0, 512 * sizeof(int), stream);
  bhist_kernel<<<nbE, 256, 0, stream>>>(adj_rows, bcnt);
  bscan_kernel<<<1, 512, 0, stream>>>(bcnt, gcursor, bbase);
  passA_kernel<<<nbE, 256, 0, stream>>>(
      adj_rows, adj_cols, adj_vals, flag, gcursor, abuf);
  passB_kernel<<<NBUCK, 256, 0, stream>>>(abuf, bbase, bcnt, offs, counts,
                                          sedge);

  gather_kernel<<<M3 / 4, 256, 0, stream>>>(sedge, counts, offs, ego0, prop);
  transform_attn_kernel<<<(N_NODES + 63) / 64, 256, 0, stream>>>(
      prop, rela_f, W_gc, 0, flag, ego1);
  gather_kernel<<<M3 / 4, 256, 0, stream>>>(sedge, counts, offs, ego1, prop);
  transform_attn_kernel<<<(N_NODES + 63) / 64, 256, 0, stream>>>(
      prop, rela_f + 192, W_gc, 4096, flag, ego2);

  final_kernel<<<(N_NODES + 63) / 64, 256, 0, stream>>>(
      ego0, ego1, ego2, gru_w, gru_b, tra, flag, d_out);
}

// Round 4
// 757.359 us; speedup vs baseline: 1.5592x; 1.0274x over previous
//
#include <hip/hip_runtime.h>
#include <hip/hip_bf16.h>

#define N_USERS 70000
#define N_ITEMS 30000
#define N_NODES 100000
#define RD 192      // R*D
#define EE 1600000
#define NE3 4800000
#define M3 300000   // 3 * N_NODES segments
#define NSUB 98     // ceil(100000/1024) row sub-buckets
#define NBUCK 294   // 3 * NSUB

// output element offsets (dtype-independent)
#define OFF_U    0
#define OFF_I    13440000
#define OFF_IZ   19200000   // zero row (item index 30000)
#define OFF_RELA 19200192
#define OFF_S1   19200384
#define OFF_S2   19270384

typedef __hip_bfloat16 bf16;
typedef unsigned long long u64;
typedef __attribute__((ext_vector_type(8))) short short8;
typedef __attribute__((ext_vector_type(8))) unsigned short ushort8;
typedef __attribute__((ext_vector_type(4))) float f32x4;

__device__ __forceinline__ float b2f(bf16 v) { return __bfloat162float(v); }

union bfbits { bf16 b; unsigned short u; };

__device__ __forceinline__ float bits2f(unsigned short u) {
  bfbits x; x.u = u; return b2f(x.b);
}
__device__ __forceinline__ unsigned short f2bits(float f) {
  bfbits x; x.b = __float2bfloat16(f); return x.u;
}

// dtype-adaptive IO: f32 -> fp32 arrays, else bf16 arrays
__device__ __forceinline__ float loadf(const void* p, int i, bool f32) {
  return f32 ? ((const float*)p)[i] : b2f(((const bf16*)p)[i]);
}
__device__ __forceinline__ void storef(void* p, int i, float v, bool f32) {
  if (f32) ((float*)p)[i] = v;
  else ((bf16*)p)[i] = __float2bfloat16(v);
}

__device__ __forceinline__ float wave_sum(float v) {
#pragma unroll
  for (int off = 32; off >= 1; off >>= 1) v += __shfl_xor(v, off, 64);
  return v;
}

__global__ void detect_kernel(const unsigned short* __restrict__ ue,
                              int* __restrict__ flag) {
  __shared__ int s;
  int t = threadIdx.x;
  if (t == 0) s = 0;
  __syncthreads();
  int big = 0;
  for (int j = t; j < 8192; j += 256) {
    int e = (ue[j] >> 7) & 0xFF;
    if (e >= 127) big = 1;
  }
  if (big) atomicOr(&s, 1);
  __syncthreads();
  if (t == 0) *flag = s;
}

__global__ void zero_row_kernel(void* out, const int* __restrict__ flag) {
  bool f32 = *flag != 0;
  storef(out, OFF_IZ + (int)threadIdx.x, 0.f, f32);  // 192 threads
}

// rela chain: rela0=rel_emb, rela1=rela0@W_rel[0], rela2=rela1@W_rel[1]
__global__ void rela_kernel(const void* __restrict__ rel_emb,
                            const void* __restrict__ W_rel,
                            const int* __restrict__ flag,
                            float* __restrict__ rela_f, void* out) {
  bool f32 = *flag != 0;
  __shared__ float r0s[192], r1s[192];
  int t = threadIdx.x;            // 192 threads
  int i = t >> 6, d = t & 63;
  float r0 = loadf(rel_emb, t, f32);
  r0s[t] = r0;
  __syncthreads();
  float acc = 0.f;
  for (int k = 0; k < 64; ++k)
    acc += r0s[i * 64 + k] * loadf(W_rel, k * 64 + d, f32);
  r1s[t] = acc;
  __syncthreads();
  float acc2 = 0.f;
  for (int k = 0; k < 64; ++k)
    acc2 += r1s[i * 64 + k] * loadf(W_rel, 4096 + k * 64 + d, f32);
  rela_f[t] = r0;
  rela_f[192 + t] = acc;
  rela_f[384 + t] = acc2;
  storef(out, OFF_RELA + t, (r0 + acc + acc2) * (1.f / 3.f), f32);
}

// vectorized x4: one thread converts 4 contiguous dims (never crosses 64-dim
// boundary since 4 | 64)
__global__ __launch_bounds__(256) void init_kernel(
    const void* __restrict__ user_emb, const void* __restrict__ item_emb,
    const int* __restrict__ flag, bf16* __restrict__ ego0) {
  bool f32 = *flag != 0;
  int idx4 = blockIdx.x * 256 + threadIdx.x;
  if (idx4 >= N_NODES * RD / 4) return;
  int idx = idx4 << 2;
  int n = idx / RD;
  int rd = idx - n * RD;
  int d = rd & 63;
  const void* src;
  int off;
  if (n < N_USERS) { src = user_emb; off = n * 64 + d; }
  else             { src = item_emb; off = (n - N_USERS) * 64 + d; }
  ushort4 o;
  if (f32) {
    float4 fv = *(const float4*)((const float*)src + off);
    o.x = f2bits(fv.x); o.y = f2bits(fv.y); o.z = f2bits(fv.z); o.w = f2bits(fv.w);
  } else {
    o = *(const ushort4*)((const unsigned short*)src + off);
  }
  *(ushort4*)(ego0 + idx) = o;
}

// ---- CSR build (hierarchical; no 300K global-atomic histogram) ----
// Stage 1: per-block LDS histogram of the 294 (rel, row>>10) buckets.
__global__ __launch_bounds__(256) void bhist_kernel(
    const int* __restrict__ rows, int* __restrict__ bcnt) {
  __shared__ int h[NBUCK];
  int t = threadIdx.x;
  for (int j = t; j < NBUCK; j += 256) h[j] = 0;
  __syncthreads();
  int base = blockIdx.x * 4096;
  int m = min(4096, NE3 - base);
  for (int j = t; j < m; j += 256) {
    int idx = base + j;
    int i = idx / EE;
    int r = rows[idx];
    atomicAdd(&h[i * NSUB + (r >> 10)], 1);
  }
  __syncthreads();
  for (int j = t; j < NBUCK; j += 256)
    if (h[j]) atomicAdd(&bcnt[j], h[j]);
}

// Stage 2: exclusive scan of 294 bucket counts -> bucket bases.
// Writes both gcursor (mutated by passA) and bbase (read by passB).
__global__ __launch_bounds__(512) void bscan_kernel(
    const int* __restrict__ bcnt, int* __restrict__ gcursor,
    int* __restrict__ bbase) {
  __shared__ int s[512];
  int t = threadIdx.x;
  int x = (t < NBUCK) ? bcnt[t] : 0;
  s[t] = x;
  __syncthreads();
  for (int off = 1; off < 512; off <<= 1) {
    int y = (t >= off) ? s[t - off] : 0;
    __syncthreads();
    s[t] += y;
    __syncthreads();
  }
  if (t < NBUCK) {
    int e = s[t] - x;
    gcursor[t] = e;
    bbase[t] = e;
  }
}

// Pass A: bucket edges into 294 (rel, row>>10) buckets; runs are
// block-contiguous -> L2 coalesces lines. Packed u64: rowlo<<48|col<<16|bf16
__global__ __launch_bounds__(256) void passA_kernel(
    const int* __restrict__ rows, const int* __restrict__ cols,
    const void* __restrict__ vals, const int* __restrict__ flag,
    int* __restrict__ gcursor, u64* __restrict__ abuf) {
  bool f32 = *flag != 0;
  __shared__ u64 pk[4096];
  __shared__ unsigned short bk[4096];
  __shared__ int cnt[NBUCK], pos[NBUCK], gbase[NBUCK];
  int t = threadIdx.x;
  for (int j = t; j < NBUCK; j += 256) { cnt[j] = 0; pos[j] = 0; }
  __syncthreads();
  int base = blockIdx.x * 4096;
  int m = min(4096, NE3 - base);
  for (int j = t; j < m; j += 256) {
    int idx = base + j;
    int i = idx / EE;
    int r = rows[idx];
    int c = cols[idx];
    unsigned short vb =
        f32 ? f2bits(((const float*)vals)[idx])
            : ((const unsigned short*)vals)[idx];
    int sub = r >> 10;
    int b = i * NSUB + sub;
    pk[j] = ((u64)(r & 1023) << 48) | ((u64)(unsigned)c << 16) | vb;
    bk[j] = (unsigned short)b;
    atomicAdd(&cnt[b], 1);
  }
  __syncthreads();
  for (int j = t; j < NBUCK; j += 256)
    if (cnt[j] > 0) gbase[j] = atomicAdd(&gcursor[j], cnt[j]);
  __syncthreads();
  for (int j = t; j < m; j += 256) {
    int b = bk[j];
    int p = atomicAdd(&pos[b], 1);
    abuf[gbase[b] + p] = pk[j];
  }
}

// Pass B: one block per bucket. Builds the within-bucket row CSR in LDS
// (1024-bin histogram + scan over the bucket's edges), writes offs/counts
// for its contiguous segment range, then scatters edges to sedge.
// sedge payload: .x = precomputed ego BYTE offset (col*384 + rel*128),
//                .y = f32 edge weight bits
__global__ __launch_bounds__(256) void passB_kernel(
    const u64* __restrict__ abuf, const int* __restrict__ bbase,
    const int* __restrict__ bcnt, int* __restrict__ offs,
    int* __restrict__ counts, int2* __restrict__ sedge) {
  __shared__ int hist[1024];   // per-row counts, then global cursors
  __shared__ int s[256];
  int b = blockIdx.x;
  int rel = b / NSUB, sub = b - rel * NSUB;
  int r0 = sub << 10;
  int nr = min(1024, N_NODES - r0);   // 1024 or 672; always %4==0
  int gi = rel * N_NODES + r0;
  int t = threadIdx.x;
  for (int j = t; j < 1024; j += 256) hist[j] = 0;
  __syncthreads();
  int start = bbase[b];
  int cnt = bcnt[b];
  int end = start + cnt;
  for (int e = start + t; e < end; e += 256)
    atomicAdd(&hist[(int)(abuf[e] >> 48)], 1);
  __syncthreads();
  // exclusive scan over 1024 bins: 4 sequential per thread + 256-wide scan
  int j0 = t << 2;
  int a0 = hist[j0], a1 = hist[j0 + 1], a2 = hist[j0 + 2], a3 = hist[j0 + 3];
  int lsum = a0 + a1 + a2 + a3;
  s[t] = lsum;
  __syncthreads();
  for (int off = 1; off < 256; off <<= 1) {
    int y = (t >= off) ? s[t - off] : 0;
    __syncthreads();
    s[t] += y;
    __syncthreads();
  }
  int o0 = start + s[t] - lsum;
  int o1 = o0 + a0, o2 = o1 + a1, o3 = o2 + a2;
  // all hist reads completed before the scan barriers -> safe to overwrite
  hist[j0] = o0; hist[j0 + 1] = o1; hist[j0 + 2] = o2; hist[j0 + 3] = o3;
  if (j0 < nr) {
    *(int4*)(offs + gi + j0) = make_int4(o0, o1, o2, o3);
    *(int4*)(counts + gi + j0) = make_int4(a0, a1, a2, a3);
  }
  __syncthreads();
  int rbase = rel * 128;
  for (int e = start + t; e < end; e += 256) {
    u64 w = abuf[e];
    int rowlo = (int)(w >> 48);
    int c = (int)((w >> 16) & 0x3FFFF);
    float v = bits2f((unsigned short)(w & 0xFFFF));
    int p = atomicAdd(&hist[rowlo], 1);
    int2 eo; eo.x = c * 384 + rbase; eo.y = __float_as_int(v);
    sedge[p] = eo;
  }
}

// one wave per (node, relation) segment. k=8 packing: 8 lanes per edge, each
// lane loads dwordx4 (8 dims). One gather instruction = 8 edges = 8 cache
// lines in flight; batch of 16 edges = 2 gathers + 2 header loads (vs 16
// VMEM at k=2). Tail = single double-masked 16-edge batch. Epilogue: 3-step
// shfl_xor reduce over edge groups; lanes g==0 store dwordx4.
__global__ __launch_bounds__(256, 8) void gather_kernel(
    const int2* __restrict__ sedge, const int* __restrict__ counts,
    const int* __restrict__ offs, const bf16* __restrict__ ego,
    bf16* __restrict__ prop) {
  int seg = blockIdx.x * 4 + (threadIdx.x >> 6);   // i*N_NODES + n
  int lane = threadIdx.x & 63;
  int g = lane >> 3;           // edge group 0..7
  int d8 = lane & 7;           // dim octet: dims 8*d8 .. 8*d8+7
  unsigned voff = (unsigned)(d8 << 4);   // byte offset within 128B line
  int i = seg / N_NODES;
  int n = seg - i * N_NODES;
  int base = offs[seg];
  int cnt = counts[seg];
  const char* egob = (const char*)ego;
  const int2* hp = sedge + base + g;
  float a0 = 0.f, a1 = 0.f, a2 = 0.f, a3 = 0.f;
  float a4 = 0.f, a5 = 0.f, a6 = 0.f, a7 = 0.f;
#define ACCUM(dv, vv)                                        \
  do {                                                       \
    a0 = fmaf(__int_as_float((dv).x << 16), (vv), a0);       \
    a1 = fmaf(__int_as_float((dv).x & 0xffff0000u), (vv), a1); \
    a2 = fmaf(__int_as_float((dv).y << 16), (vv), a2);       \
    a3 = fmaf(__int_as_float((dv).y & 0xffff0000u), (vv), a3); \
    a4 = fmaf(__int_as_float((dv).z << 16), (vv), a4);       \
    a5 = fmaf(__int_as_float((dv).z & 0xffff0000u), (vv), a5); \
    a6 = fmaf(__int_as_float((dv).w << 16), (vv), a6);       \
    a7 = fmaf(__int_as_float((dv).w & 0xffff0000u), (vv), a7); \
  } while (0)
  int j = 0;
  int nfull = cnt & ~15;
  for (; j < nfull; j += 16) {
    int2 h0 = hp[j];
    int2 h1 = hp[j + 8];
    uint4 dA = *(const uint4*)(egob + ((unsigned)h0.x + voff));
    uint4 dB = *(const uint4*)(egob + ((unsigned)h1.x + voff));
    float v0 = __int_as_float(h0.y);
    float v1 = __int_as_float(h1.y);
    ACCUM(dA, v0);
    ACCUM(dB, v1);
  }
  int rem = cnt - j;
  if (rem > 0) {
    int iA = min(g, rem - 1);
    int iB = min(8 + g, rem - 1);
    int2 h0 = sedge[base + j + iA];
    int2 h1 = sedge[base + j + iB];
    uint4 dA = *(const uint4*)(egob + ((unsigned)h0.x + voff));
    uint4 dB = *(const uint4*)(egob + ((unsigned)h1.x + voff));
    float v0 = (g < rem) ? __int_as_float(h0.y) : 0.f;
    float v1 = (8 + g < rem) ? __int_as_float(h1.y) : 0.f;
    ACCUM(dA, v0);
    ACCUM(dB, v1);
  }
#undef ACCUM
  // reduce across the 8 edge groups (same d8, different g)
#pragma unroll
  for (int off = 8; off <= 32; off <<= 1) {
    a0 += __shfl_xor(a0, off, 64);
    a1 += __shfl_xor(a1, off, 64);
    a2 += __shfl_xor(a2, off, 64);
    a3 += __shfl_xor(a3, off, 64);
    a4 += __shfl_xor(a4, off, 64);
    a5 += __shfl_xor(a5, off, 64);
    a6 += __shfl_xor(a6, off, 64);
    a7 += __shfl_xor(a7, off, 64);
  }
  if (g == 0) {
    uint4 o;
    o.x = (unsigned)f2bits(a0) | ((unsigned)f2bits(a1) << 16);
    o.y = (unsigned)f2bits(a2) | ((unsigned)f2bits(a3) << 16);
    o.z = (unsigned)f2bits(a4) | ((unsigned)f2bits(a5) << 16);
    o.w = (unsigned)f2bits(a6) | ((unsigned)f2bits(a7) << 16);
    *(uint4*)((char*)prop + (size_t)(n * RD + i * 64) * 2 + voff) = o;
  }
}

__device__ __forceinline__ float attn_row(float a, float b, float c,
                                          float e0, float e1, float e2) {
  float m = fmaxf(a, fmaxf(b, c));
  float w0 = __expf(a - m), w1 = __expf(b - m), w2 = __expf(c - m);
  float inv = 1.f / (w0 + w1 + w2);
  return (w0 * e0 + w1 * e1 + w2 * e2) * inv;
}

// MFMA transform: X(300000x64) @ W(64x64), X = prop * rela (per-relation).
// Block = 64 nodes = 192 X-rows. Wave w owns W cols [16w,16w+16).
// 12 row-tiles x 2 mfma_16x16x32_bf16.
// est stored bf16 TRANSPOSED: est_t[col][row], stride 198 (odd-dword ->
// Gram reads land 2 lanes/bank = conflict-free). LDS 25.3KB (was 50.7KB f32)
// -> ~2x occupancy. MFMA results packed as 2x u32 stores (4 rows/lane).
__global__ __launch_bounds__(256, 4) void transform_attn_kernel(
    const bf16* __restrict__ prop, const float* __restrict__ rela_k,
    const void* __restrict__ Wgc, int wgc_off, const int* __restrict__ flag,
    bf16* __restrict__ ego_out) {
  bool f32 = *flag != 0;
  __shared__ __align__(16) unsigned short est_t[64 * 198];
  int t = threadIdx.x, lane = t & 63, wave = t >> 6;
  int quad = lane >> 4, m = lane & 15;
  int wcol = wave * 16 + m;   // this lane's D column (global 0..63)
  // B fragments (one-time): B[k=quad*8+j][n=wcol]
  short8 b0, b1;
#pragma unroll
  for (int j = 0; j < 8; ++j) {
    int k0 = quad * 8 + j;
    b0[j] = (short)f2bits(loadf(Wgc, wgc_off + k0 * 64 + wcol, f32));
    b1[j] = (short)f2bits(loadf(Wgc, wgc_off + (k0 + 32) * 64 + wcol, f32));
  }
  // rela values at this lane's k positions, for all 3 relations
  float relv0[16], relv1[16], relv2[16];
#pragma unroll
  for (int j = 0; j < 8; ++j) {
    int k0 = quad * 8 + j;
    relv0[j] = rela_k[k0];        relv0[8 + j] = rela_k[32 + k0];
    relv1[j] = rela_k[64 + k0];   relv1[8 + j] = rela_k[96 + k0];
    relv2[j] = rela_k[128 + k0];  relv2[8 + j] = rela_k[160 + k0];
  }
  int n0 = blockIdx.x * 64;
  int row0 = n0 * 3;
#pragma unroll
  for (int tr = 0; tr < 12; ++tr) {
    int rl = tr * 16 + m;            // local A row
    int row = row0 + rl;
    int row_c = row < M3 ? row : 0;
    int i = rl % 3;                  // relation of this row (row0 % 3 == 0)
    const ushort8* pp = (const ushort8*)(prop + (size_t)row_c * 64 + quad * 8);
    ushort8 x0 = pp[0];              // k = quad*8 .. +7
    ushort8 x1 = pp[4];              // k+32
    short8 a0, a1;
#pragma unroll
    for (int j = 0; j < 8; ++j) {
      float r0 = (i == 0) ? relv0[j] : (i == 1 ? relv1[j] : relv2[j]);
      float r1 = (i == 0) ? relv0[8 + j] : (i == 1 ? relv1[8 + j] : relv2[8 + j]);
      a0[j] = (short)f2bits(bits2f(x0[j]) * r0);
      a1[j] = (short)f2bits(bits2f(x1[j]) * r1);
    }
    f32x4 acc = {0.f, 0.f, 0.f, 0.f};
    acc = __builtin_amdgcn_mfma_f32_16x16x32_bf16(a0, b0, acc, 0, 0, 0);
    acc = __builtin_amdgcn_mfma_f32_16x16x32_bf16(a1, b1, acc, 0, 0, 0);
    float v0 = acc[0]; v0 = v0 > 0.f ? v0 : 0.01f * v0;
    float v1 = acc[1]; v1 = v1 > 0.f ? v1 : 0.01f * v1;
    float v2 = acc[2]; v2 = v2 > 0.f ? v2 : 0.01f * v2;
    float v3 = acc[3]; v3 = v3 > 0.f ? v3 : 0.01f * v3;
    unsigned w0 = (unsigned)f2bits(v0) | ((unsigned)f2bits(v1) << 16);
    unsigned w1 = (unsigned)f2bits(v2) | ((unsigned)f2bits(v3) << 16);
    unsigned* p32 = (unsigned*)(est_t + wcol * 198 + tr * 16 + quad * 4);
    p32[0] = w0; p32[1] = w1;
  }
  __syncthreads();
  const float sc = 0.088388347648318447f;  // 1/sqrt(128)
  for (int jj = 0; jj < 16; ++jj) {
    int nl = wave * 16 + jj;
    int n = n0 + nl;
    if (n >= N_NODES) break;
    int rb = lane * 198 + 3 * nl;
    float e0 = bits2f(est_t[rb]);
    float e1 = bits2f(est_t[rb + 1]);
    float e2 = bits2f(est_t[rb + 2]);
    float s00 = wave_sum(e0 * e0);
    float s01 = wave_sum(e0 * e1);
    float s02 = wave_sum(e0 * e2);
    float s11 = wave_sum(e1 * e1);
    float s12 = wave_sum(e1 * e2);
    float s22 = wave_sum(e2 * e2);
    float o0 = attn_row(s00 * sc, s01 * sc, s02 * sc, e0, e1, e2);
    float o1 = attn_row(s01 * sc, s11 * sc, s12 * sc, e0, e1, e2);
    float o2 = attn_row(s02 * sc, s12 * sc, s22 * sc, e0, e1, e2);
    int base = n * RD + lane;
    ego_out[base] = __float2bfloat16(o0);
    ego_out[base + 64] = __float2bfloat16(o1);
    ego_out[base + 128] = __float2bfloat16(o2);
  }
}

// final: attention row 2, outputs, and MFMA GRU + scores.
// fmat stored bf16, row stride 72 (16B-aligned rows): LDS 28KB (was 51KB)
// -> 2x+ occupancy. Phase-2 A-frags via 2x ds_read_b128 (no conversion).
// Score partials accumulated over i in registers; single reduce per (tr,r).
__global__ __launch_bounds__(256, 4) void final_kernel(
    const bf16* __restrict__ ego0, const bf16* __restrict__ ego1,
    const bf16* __restrict__ ego2, const void* __restrict__ gru_w,
    const void* __restrict__ gru_b, const void* __restrict__ tra,
    const int* __restrict__ flag, void* out) {
  bool f32 = *flag != 0;
  __shared__ __align__(16) unsigned short fmatu[192 * 72];
  __shared__ float sc_lds[128];   // [64 nodes][2]
  int t = threadIdx.x, lane = t & 63, wave = t >> 6;
  int quad = lane >> 4, m = lane & 15;
  int wcol = wave * 16 + m;
  if (t < 128) sc_lds[t] = 0.f;
  // B-frags for gru_w[0..2]; biases; tra scalars (per-lane)
  short8 bw[3][2];
#pragma unroll
  for (int i = 0; i < 3; ++i)
#pragma unroll
    for (int j = 0; j < 8; ++j) {
      int k0 = quad * 8 + j;
      bw[i][0][j] = (short)f2bits(loadf(gru_w, i * 4096 + k0 * 64 + wcol, f32));
      bw[i][1][j] =
          (short)f2bits(loadf(gru_w, i * 4096 + (k0 + 32) * 64 + wcol, f32));
    }
  float bias0 = loadf(gru_b, wcol, f32);
  float bias1 = loadf(gru_b, 64 + wcol, f32);
  float bias2 = loadf(gru_b, 128 + wcol, f32);
  float ts0 = loadf(tra, wcol, f32);        // tra[0][:64]   (tgt -> sc1)
  float ts1 = loadf(tra, 64 + wcol, f32);   // tra[0][64:]   (aux1 -> sc1)
  float ts2 = loadf(tra, 128 + wcol, f32);  // tra[1][:64]   (tgt -> sc2)
  float ts3 = loadf(tra, 192 + wcol, f32);  // tra[1][64:]   (aux2 -> sc2)

  int n0 = blockIdx.x * 64;
  // Phase 1: attention + u/i outputs + fmat
  for (int jj = 0; jj < 16; ++jj) {
    int nl = wave * 16 + jj;
    int n = n0 + nl;
    float f0 = 0.f, f1 = 0.f, f2 = 0.f;
    if (n < N_NODES) {
      int b0i = n * RD + lane;
      float a0 = b2f(ego0[b0i]) + b2f(ego1[b0i]) + b2f(ego2[b0i]);
      float a1 =
          b2f(ego0[b0i + 64]) + b2f(ego1[b0i + 64]) + b2f(ego2[b0i + 64]);
      float a2 =
          b2f(ego0[b0i + 128]) + b2f(ego1[b0i + 128]) + b2f(ego2[b0i + 128]);
      float s20 = wave_sum(a2 * a0);
      float s21 = wave_sum(a2 * a1);
      float s22 = wave_sum(a2 * a2);
      float mid2 = attn_row(s20, s21, s22, a0, a1, a2);
      f0 = a0 * (1.f / 3.f);
      f1 = a1 * (1.f / 3.f);
      f2 = mid2 * (1.f / 3.f);
      if (n < N_USERS) {
        int ob = OFF_U + n * RD + lane;
        storef(out, ob, f0, f32);
        storef(out, ob + 64, f1, f32);
        storef(out, ob + 128, f2, f32);
      } else {
        int ob = OFF_I + (n - N_USERS) * RD + lane;
        storef(out, ob, f0, f32);
        storef(out, ob + 64, f1, f32);
        storef(out, ob + 128, f2, f32);
      }
    }
    fmatu[(0 * 64 + nl) * 72 + lane] = f2bits(f0);
    fmatu[(1 * 64 + nl) * 72 + lane] = f2bits(f1);
    fmatu[(2 * 64 + nl) * 72 + lane] = f2bits(f2);
  }
  __syncthreads();
  // Phase 2: 3 GEMMs (64x64 @ 64x64); score partials accumulated over i
  float p1a[4][4], p2a[4][4];
#pragma unroll
  for (int tr = 0; tr < 4; ++tr)
#pragma unroll
    for (int r = 0; r < 4; ++r) { p1a[tr][r] = 0.f; p2a[tr][r] = 0.f; }
#pragma unroll
  for (int i = 0; i < 3; ++i) {
    float bias = (i == 0) ? bias0 : (i == 1 ? bias1 : bias2);
#pragma unroll
    for (int tr = 0; tr < 4; ++tr) {
      int arow = (i * 64 + tr * 16 + m) * 72;
      short8 a0 = *(const short8*)(fmatu + arow + quad * 8);
      short8 a1 = *(const short8*)(fmatu + arow + 32 + quad * 8);
      f32x4 acc = {0.f, 0.f, 0.f, 0.f};
      acc = __builtin_amdgcn_mfma_f32_16x16x32_bf16(a0, bw[i][0], acc, 0, 0, 0);
      acc = __builtin_amdgcn_mfma_f32_16x16x32_bf16(a1, bw[i][1], acc, 0, 0, 0);
#pragma unroll
      for (int r = 0; r < 4; ++r) {
        int nl = tr * 16 + quad * 4 + r;
        float y = acc[r] + bias;
        float f = bits2f(fmatu[(i * 64 + nl) * 72 + wcol]);
        float prod = f * y;
        if (i == 0) p1a[tr][r] += prod * ts1;
        else if (i == 1) p2a[tr][r] += prod * ts3;
        else { p1a[tr][r] += prod * ts0; p2a[tr][r] += prod * ts2; }
      }
    }
  }
  // single reduce per (tr,r) over the 16 m-lanes, then LDS accumulate
#pragma unroll
  for (int tr = 0; tr < 4; ++tr)
#pragma unroll
    for (int r = 0; r < 4; ++r) {
      float p1 = p1a[tr][r], p2 = p2a[tr][r];
#pragma unroll
      for (int off = 1; off < 16; off <<= 1) {
        p1 += __shfl_xor(p1, off, 64);
        p2 += __shfl_xor(p2, off, 64);
      }
      if (m == 0) {
        int nl = tr * 16 + quad * 4 + r;
        atomicAdd(&sc_lds[nl * 2], p1);
        atomicAdd(&sc_lds[nl * 2 + 1], p2);
      }
    }
  __syncthreads();
  // Phase 3: score outputs
  if (t < 64) {
    int n = n0 + t;
    if (n < N_USERS) {
      storef(out, OFF_S1 + n, sc_lds[t * 2], f32);
      storef(out, OFF_S2 + n, sc_lds[t * 2 + 1], f32);
    }
  }
}

extern "C" void kernel_launch(void* const* d_in, const int* in_sizes, int n_in,
                              void* d_out, int out_size, void* d_ws,
                              size_t ws_size, hipStream_t stream) {
  const void* user_emb = d_in[0];
  const void* item_emb = d_in[1];
  const void* rel_emb = d_in[2];
  const void* W_gc = d_in[3];
  const void* W_rel = d_in[4];
  const void* gru_w = d_in[5];
  const void* gru_b = d_in[6];
  const void* tra = d_in[7];
  const void* adj_vals = d_in[8];
  const int* adj_rows = (const int*)d_in[9];
  const int* adj_cols = (const int*)d_in[10];

  // ws layout (~230 MB)
  int* flag = (int*)d_ws;
  float* wsf = (float*)d_ws;
  float* rela_f = wsf + 16;                       // 576 floats
  int* counts = (int*)(wsf + 1024);               // 300k
  int* offs = counts + M3;                        // 300k
  int* gcursor = offs + M3;                       // 512
  int* bcnt = gcursor + 512;                      // 512
  int* bbase = bcnt + 512;                        // 512
  u64* abuf = (u64*)(bbase + 512);                // 4.8M u64 (8B-aligned)
  int2* sedge = (int2*)(abuf + NE3);              // 4.8M int2
  bf16* ego0 = (bf16*)(sedge + NE3);              // 19.2M bf16
  bf16* ego1 = ego0 + (size_t)N_NODES * RD;
  bf16* ego2 = ego1 + (size_t)N_NODES * RD;
  bf16* prop = ego2 + (size_t)N_NODES * RD;

  const int nbE = (NE3 + 4095) / 4096;            // 1172

  detect_kernel<<<1, 256, 0, stream>>>((const unsigned short*)user_emb, flag);
  rela_kernel<<<1, 192, 0, stream>>>(rel_emb, W_rel, flag, rela_f, d_out);
  zero_row_kernel<<<1, 192, 0, stream>>>(d_out, flag);
  init_kernel<<<(N_NODES * RD / 4 + 255) / 256, 256, 0, stream>>>(
      user_emb, item_emb, flag, ego0);

  (void)hipMemsetAsync(bcnt, 0, 512 * sizeof(int), stream);
  bhist_kernel<<<nbE, 256, 0, stream>>>(adj_rows, bcnt);
  bscan_kernel<<<1, 512, 0, stream>>>(bcnt, gcursor, bbase);
  passA_kernel<<<nbE, 256, 0, stream>>>(
      adj_rows, adj_cols, adj_vals, flag, gcursor, abuf);
  passB_kernel<<<NBUCK, 256, 0, stream>>>(abuf, bbase, bcnt, offs, counts,
                                          sedge);

  gather_kernel<<<M3 / 4, 256, 0, stream>>>(sedge, counts, offs, ego0, prop);
  transform_attn_kernel<<<(N_NODES + 63) / 64, 256, 0, stream>>>(
      prop, rela_f, W_gc, 0, flag, ego1);
  gather_kernel<<<M3 / 4, 256, 0, stream>>>(sedge, counts, offs, ego1, prop);
  transform_attn_kernel<<<(N_NODES + 63) / 64, 256, 0, stream>>>(
      prop, rela_f + 192, W_gc, 4096, flag, ego2);

  final_kernel<<<(N_NODES + 63) / 64, 256, 0, stream>>>(
      ego0, ego1, ego2, gru_w, gru_b, tra, flag, d_out);
}

// Round 5
// 735.042 us; speedup vs baseline: 1.6065x; 1.0304x over previous
//
#include <hip/hip_runtime.h>
#include <hip/hip_bf16.h>

#define N_USERS 70000
#define N_ITEMS 30000
#define N_NODES 100000
#define RD 192      // R*D
#define EE 1600000
#define NE3 4800000
#define M3 300000   // 3 * N_NODES segments
#define NSUB 98     // ceil(100000/1024) row sub-buckets
#define NBUCK 294   // 3 * NSUB

// output element offsets (dtype-independent)
#define OFF_U    0
#define OFF_I    13440000
#define OFF_IZ   19200000   // zero row (item index 30000)
#define OFF_RELA 19200192
#define OFF_S1   19200384
#define OFF_S2   19270384

typedef __hip_bfloat16 bf16;
typedef unsigned long long u64;
typedef __attribute__((ext_vector_type(8))) short short8;
typedef __attribute__((ext_vector_type(8))) unsigned short ushort8;
typedef __attribute__((ext_vector_type(4))) float f32x4;

__device__ __forceinline__ float b2f(bf16 v) { return __bfloat162float(v); }

union bfbits { bf16 b; unsigned short u; };

__device__ __forceinline__ float bits2f(unsigned short u) {
  bfbits x; x.u = u; return b2f(x.b);
}
__device__ __forceinline__ unsigned short f2bits(float f) {
  bfbits x; x.b = __float2bfloat16(f); return x.u;
}

// dtype-adaptive IO: f32 -> fp32 arrays, else bf16 arrays
__device__ __forceinline__ float loadf(const void* p, int i, bool f32) {
  return f32 ? ((const float*)p)[i] : b2f(((const bf16*)p)[i]);
}
__device__ __forceinline__ void storef(void* p, int i, float v, bool f32) {
  if (f32) ((float*)p)[i] = v;
  else ((bf16*)p)[i] = __float2bfloat16(v);
}

__device__ __forceinline__ float wave_sum(float v) {
#pragma unroll
  for (int off = 32; off >= 1; off >>= 1) v += __shfl_xor(v, off, 64);
  return v;
}

__global__ void detect_kernel(const unsigned short* __restrict__ ue,
                              int* __restrict__ flag) {
  __shared__ int s;
  int t = threadIdx.x;
  if (t == 0) s = 0;
  __syncthreads();
  int big = 0;
  for (int j = t; j < 8192; j += 256) {
    int e = (ue[j] >> 7) & 0xFF;
    if (e >= 127) big = 1;
  }
  if (big) atomicOr(&s, 1);
  __syncthreads();
  if (t == 0) *flag = s;
}

__global__ void zero_row_kernel(void* out, const int* __restrict__ flag) {
  bool f32 = *flag != 0;
  storef(out, OFF_IZ + (int)threadIdx.x, 0.f, f32);  // 192 threads
}

// rela chain: rela0=rel_emb, rela1=rela0@W_rel[0], rela2=rela1@W_rel[1]
__global__ void rela_kernel(const void* __restrict__ rel_emb,
                            const void* __restrict__ W_rel,
                            const int* __restrict__ flag,
                            float* __restrict__ rela_f, void* out) {
  bool f32 = *flag != 0;
  __shared__ float r0s[192], r1s[192];
  int t = threadIdx.x;            // 192 threads
  int i = t >> 6, d = t & 63;
  float r0 = loadf(rel_emb, t, f32);
  r0s[t] = r0;
  __syncthreads();
  float acc = 0.f;
  for (int k = 0; k < 64; ++k)
    acc += r0s[i * 64 + k] * loadf(W_rel, k * 64 + d, f32);
  r1s[t] = acc;
  __syncthreads();
  float acc2 = 0.f;
  for (int k = 0; k < 64; ++k)
    acc2 += r1s[i * 64 + k] * loadf(W_rel, 4096 + k * 64 + d, f32);
  rela_f[t] = r0;
  rela_f[192 + t] = acc;
  rela_f[384 + t] = acc2;
  storef(out, OFF_RELA + t, (r0 + acc + acc2) * (1.f / 3.f), f32);
}

// vectorized x4: one thread converts 4 contiguous dims (never crosses 64-dim
// boundary since 4 | 64)
__global__ __launch_bounds__(256) void init_kernel(
    const void* __restrict__ user_emb, const void* __restrict__ item_emb,
    const int* __restrict__ flag, bf16* __restrict__ ego0) {
  bool f32 = *flag != 0;
  int idx4 = blockIdx.x * 256 + threadIdx.x;
  if (idx4 >= N_NODES * RD / 4) return;
  int idx = idx4 << 2;
  int n = idx / RD;
  int rd = idx - n * RD;
  int d = rd & 63;
  const void* src;
  int off;
  if (n < N_USERS) { src = user_emb; off = n * 64 + d; }
  else             { src = item_emb; off = (n - N_USERS) * 64 + d; }
  ushort4 o;
  if (f32) {
    float4 fv = *(const float4*)((const float*)src + off);
    o.x = f2bits(fv.x); o.y = f2bits(fv.y); o.z = f2bits(fv.z); o.w = f2bits(fv.w);
  } else {
    o = *(const ushort4*)((const unsigned short*)src + off);
  }
  *(ushort4*)(ego0 + idx) = o;
}

// ---- CSR build (hierarchical; no 300K global-atomic histogram) ----
// Stage 1: per-block LDS histogram of the 294 (rel, row>>10) buckets.
__global__ __launch_bounds__(256) void bhist_kernel(
    const int* __restrict__ rows, int* __restrict__ bcnt) {
  __shared__ int h[NBUCK];
  int t = threadIdx.x;
  for (int j = t; j < NBUCK; j += 256) h[j] = 0;
  __syncthreads();
  int base = blockIdx.x * 4096;
  int m = min(4096, NE3 - base);
  for (int j = t; j < m; j += 256) {
    int idx = base + j;
    int i = idx / EE;
    int r = rows[idx];
    atomicAdd(&h[i * NSUB + (r >> 10)], 1);
  }
  __syncthreads();
  for (int j = t; j < NBUCK; j += 256)
    if (h[j]) atomicAdd(&bcnt[j], h[j]);
}

// Stage 2: exclusive scan of 294 bucket counts -> bucket bases.
// Writes both gcursor (mutated by passA) and bbase (read by passB).
__global__ __launch_bounds__(512) void bscan_kernel(
    const int* __restrict__ bcnt, int* __restrict__ gcursor,
    int* __restrict__ bbase) {
  __shared__ int s[512];
  int t = threadIdx.x;
  int x = (t < NBUCK) ? bcnt[t] : 0;
  s[t] = x;
  __syncthreads();
  for (int off = 1; off < 512; off <<= 1) {
    int y = (t >= off) ? s[t - off] : 0;
    __syncthreads();
    s[t] += y;
    __syncthreads();
  }
  if (t < NBUCK) {
    int e = s[t] - x;
    gcursor[t] = e;
    bbase[t] = e;
  }
}

// Pass A: bucket edges into 294 (rel, row>>10) buckets; runs are
// block-contiguous -> L2 coalesces lines. Packed u64: rowlo<<48|col<<16|bf16
__global__ __launch_bounds__(256) void passA_kernel(
    const int* __restrict__ rows, const int* __restrict__ cols,
    const void* __restrict__ vals, const int* __restrict__ flag,
    int* __restrict__ gcursor, u64* __restrict__ abuf) {
  bool f32 = *flag != 0;
  __shared__ u64 pk[4096];
  __shared__ unsigned short bk[4096];
  __shared__ int cnt[NBUCK], pos[NBUCK], gbase[NBUCK];
  int t = threadIdx.x;
  for (int j = t; j < NBUCK; j += 256) { cnt[j] = 0; pos[j] = 0; }
  __syncthreads();
  int base = blockIdx.x * 4096;
  int m = min(4096, NE3 - base);
  for (int j = t; j < m; j += 256) {
    int idx = base + j;
    int i = idx / EE;
    int r = rows[idx];
    int c = cols[idx];
    unsigned short vb =
        f32 ? f2bits(((const float*)vals)[idx])
            : ((const unsigned short*)vals)[idx];
    int sub = r >> 10;
    int b = i * NSUB + sub;
    pk[j] = ((u64)(r & 1023) << 48) | ((u64)(unsigned)c << 16) | vb;
    bk[j] = (unsigned short)b;
    atomicAdd(&cnt[b], 1);
  }
  __syncthreads();
  for (int j = t; j < NBUCK; j += 256)
    if (cnt[j] > 0) gbase[j] = atomicAdd(&gcursor[j], cnt[j]);
  __syncthreads();
  for (int j = t; j < m; j += 256) {
    int b = bk[j];
    int p = atomicAdd(&pos[b], 1);
    abuf[gbase[b] + p] = pk[j];
  }
}

// Pass B: one block per bucket. Builds the within-bucket row CSR in LDS
// (1024-bin histogram + scan over the bucket's edges), writes offs/counts
// for its contiguous segment range, then scatters edges to sedge.
// sedge payload: .x = precomputed ego BYTE offset (col*384 + rel*128),
//                .y = f32 edge weight bits
__global__ __launch_bounds__(256) void passB_kernel(
    const u64* __restrict__ abuf, const int* __restrict__ bbase,
    const int* __restrict__ bcnt, int* __restrict__ offs,
    int* __restrict__ counts, int2* __restrict__ sedge) {
  __shared__ int hist[1024];   // per-row counts, then global cursors
  __shared__ int s[256];
  int b = blockIdx.x;
  int rel = b / NSUB, sub = b - rel * NSUB;
  int r0 = sub << 10;
  int nr = min(1024, N_NODES - r0);   // 1024 or 672; always %4==0
  int gi = rel * N_NODES + r0;
  int t = threadIdx.x;
  for (int j = t; j < 1024; j += 256) hist[j] = 0;
  __syncthreads();
  int start = bbase[b];
  int cnt = bcnt[b];
  int end = start + cnt;
  for (int e = start + t; e < end; e += 256)
    atomicAdd(&hist[(int)(abuf[e] >> 48)], 1);
  __syncthreads();
  // exclusive scan over 1024 bins: 4 sequential per thread + 256-wide scan
  int j0 = t << 2;
  int a0 = hist[j0], a1 = hist[j0 + 1], a2 = hist[j0 + 2], a3 = hist[j0 + 3];
  int lsum = a0 + a1 + a2 + a3;
  s[t] = lsum;
  __syncthreads();
  for (int off = 1; off < 256; off <<= 1) {
    int y = (t >= off) ? s[t - off] : 0;
    __syncthreads();
    s[t] += y;
    __syncthreads();
  }
  int o0 = start + s[t] - lsum;
  int o1 = o0 + a0, o2 = o1 + a1, o3 = o2 + a2;
  // all hist reads completed before the scan barriers -> safe to overwrite
  hist[j0] = o0; hist[j0 + 1] = o1; hist[j0 + 2] = o2; hist[j0 + 3] = o3;
  if (j0 < nr) {
    *(int4*)(offs + gi + j0) = make_int4(o0, o1, o2, o3);
    *(int4*)(counts + gi + j0) = make_int4(a0, a1, a2, a3);
  }
  __syncthreads();
  int rbase = rel * 128;
  for (int e = start + t; e < end; e += 256) {
    u64 w = abuf[e];
    int rowlo = (int)(w >> 48);
    int c = (int)((w >> 16) & 0x3FFFF);
    float v = bits2f((unsigned short)(w & 0xFFFF));
    int p = atomicAdd(&hist[rowlo], 1);
    int2 eo; eo.x = c * 384 + rbase; eo.y = __float_as_int(v);
    sedge[p] = eo;
  }
}

// one wave per (node, relation) segment; relation = blockIdx.y (no divide).
// k=8 packing: 8 lanes/edge, dwordx4 = 8 dims/lane. Unified clamped loop
// (no separate tail): edge index min-clamped to cnt-1, weight cndmask'd to 0.
// 2-deep software pipeline: two 16-edge batches interleaved per loop body ->
// 4 header loads then 4 gathers in flight (32 cache lines/wave), one
// header-wait + one gather-wait per 32 edges. base/cnt readfirstlane'd to
// SGPRs (scalar loop bounds, SGPR-base addressing).
__global__ __launch_bounds__(256, 8) void gather_kernel(
    const int2* __restrict__ sedge, const int* __restrict__ counts,
    const int* __restrict__ offs, const bf16* __restrict__ ego,
    bf16* __restrict__ prop) {
  int wave = threadIdx.x >> 6;
  int n = blockIdx.x * 4 + wave;
  int rel = blockIdx.y;
  int seg = rel * N_NODES + n;
  int lane = threadIdx.x & 63;
  int g = lane >> 3;           // edge group 0..7
  int d8 = lane & 7;           // dim octet: dims 8*d8 .. 8*d8+7
  unsigned voff = (unsigned)(d8 << 4);   // byte offset within 128B line
  int base = __builtin_amdgcn_readfirstlane(offs[seg]);
  int cnt = __builtin_amdgcn_readfirstlane(counts[seg]);
  const char* egob = (const char*)ego;
  float a0 = 0.f, a1 = 0.f, a2 = 0.f, a3 = 0.f;
  float a4 = 0.f, a5 = 0.f, a6 = 0.f, a7 = 0.f;
#define ACCUM(dv, vv)                                          \
  do {                                                         \
    a0 = fmaf(__int_as_float((dv).x << 16), (vv), a0);         \
    a1 = fmaf(__int_as_float((dv).x & 0xffff0000u), (vv), a1); \
    a2 = fmaf(__int_as_float((dv).y << 16), (vv), a2);         \
    a3 = fmaf(__int_as_float((dv).y & 0xffff0000u), (vv), a3); \
    a4 = fmaf(__int_as_float((dv).z << 16), (vv), a4);         \
    a5 = fmaf(__int_as_float((dv).z & 0xffff0000u), (vv), a5); \
    a6 = fmaf(__int_as_float((dv).w << 16), (vv), a6);         \
    a7 = fmaf(__int_as_float((dv).w & 0xffff0000u), (vv), a7); \
  } while (0)
  int cm = cnt - 1;
  int nb = (cnt + 15) >> 4;    // 16-edge batches (clamped+masked)
  int j = 0;
  if (nb & 1) {
    int iA = min(g, cm), iB = min(8 + g, cm);
    int2 h0 = sedge[base + iA];
    int2 h1 = sedge[base + iB];
    uint4 dA = *(const uint4*)(egob + ((unsigned)h0.x + voff));
    uint4 dB = *(const uint4*)(egob + ((unsigned)h1.x + voff));
    float v0 = (g < cnt) ? __int_as_float(h0.y) : 0.f;
    float v1 = (8 + g < cnt) ? __int_as_float(h1.y) : 0.f;
    ACCUM(dA, v0);
    ACCUM(dB, v1);
    j = 16;
  }
  int e16 = nb << 4;
  for (; j < e16; j += 32) {
    int iA0 = min(j + g, cm),      iB0 = min(j + 8 + g, cm);
    int iA1 = min(j + 16 + g, cm), iB1 = min(j + 24 + g, cm);
    int2 h0a = sedge[base + iA0];
    int2 h1a = sedge[base + iB0];
    int2 h0b = sedge[base + iA1];
    int2 h1b = sedge[base + iB1];
    uint4 dA = *(const uint4*)(egob + ((unsigned)h0a.x + voff));
    uint4 dB = *(const uint4*)(egob + ((unsigned)h1a.x + voff));
    uint4 dC = *(const uint4*)(egob + ((unsigned)h0b.x + voff));
    uint4 dD = *(const uint4*)(egob + ((unsigned)h1b.x + voff));
    float v0 = (j + g < cnt) ? __int_as_float(h0a.y) : 0.f;
    float v1 = (j + 8 + g < cnt) ? __int_as_float(h1a.y) : 0.f;
    float v2 = (j + 16 + g < cnt) ? __int_as_float(h0b.y) : 0.f;
    float v3 = (j + 24 + g < cnt) ? __int_as_float(h1b.y) : 0.f;
    ACCUM(dA, v0);
    ACCUM(dB, v1);
    ACCUM(dC, v2);
    ACCUM(dD, v3);
  }
#undef ACCUM
  // reduce across the 8 edge groups (same d8, different g)
#pragma unroll
  for (int off = 8; off <= 32; off <<= 1) {
    a0 += __shfl_xor(a0, off, 64);
    a1 += __shfl_xor(a1, off, 64);
    a2 += __shfl_xor(a2, off, 64);
    a3 += __shfl_xor(a3, off, 64);
    a4 += __shfl_xor(a4, off, 64);
    a5 += __shfl_xor(a5, off, 64);
    a6 += __shfl_xor(a6, off, 64);
    a7 += __shfl_xor(a7, off, 64);
  }
  if (g == 0) {
    uint4 o;
    o.x = (unsigned)f2bits(a0) | ((unsigned)f2bits(a1) << 16);
    o.y = (unsigned)f2bits(a2) | ((unsigned)f2bits(a3) << 16);
    o.z = (unsigned)f2bits(a4) | ((unsigned)f2bits(a5) << 16);
    o.w = (unsigned)f2bits(a6) | ((unsigned)f2bits(a7) << 16);
    *(uint4*)((char*)prop + (size_t)(n * RD + rel * 64) * 2 + voff) = o;
  }
}

__device__ __forceinline__ float attn_row(float a, float b, float c,
                                          float e0, float e1, float e2) {
  float m = fmaxf(a, fmaxf(b, c));
  float w0 = __expf(a - m), w1 = __expf(b - m), w2 = __expf(c - m);
  float inv = 1.f / (w0 + w1 + w2);
  return (w0 * e0 + w1 * e1 + w2 * e2) * inv;
}

// MFMA transform: X(300000x64) @ W(64x64), X = prop * rela (per-relation).
// Block = 64 nodes = 192 X-rows. Wave w owns W cols [16w,16w+16).
// 12 row-tiles x 2 mfma_16x16x32_bf16.
// est stored bf16 TRANSPOSED: est_t[col][row], stride 198 (odd-dword ->
// Gram reads land 2 lanes/bank = conflict-free). LDS 25.3KB (was 50.7KB f32)
// -> ~2x occupancy. MFMA results packed as 2x u32 stores (4 rows/lane).
__global__ __launch_bounds__(256, 4) void transform_attn_kernel(
    const bf16* __restrict__ prop, const float* __restrict__ rela_k,
    const void* __restrict__ Wgc, int wgc_off, const int* __restrict__ flag,
    bf16* __restrict__ ego_out) {
  bool f32 = *flag != 0;
  __shared__ __align__(16) unsigned short est_t[64 * 198];
  int t = threadIdx.x, lane = t & 63, wave = t >> 6;
  int quad = lane >> 4, m = lane & 15;
  int wcol = wave * 16 + m;   // this lane's D column (global 0..63)
  // B fragments (one-time): B[k=quad*8+j][n=wcol]
  short8 b0, b1;
#pragma unroll
  for (int j = 0; j < 8; ++j) {
    int k0 = quad * 8 + j;
    b0[j] = (short)f2bits(loadf(Wgc, wgc_off + k0 * 64 + wcol, f32));
    b1[j] = (short)f2bits(loadf(Wgc, wgc_off + (k0 + 32) * 64 + wcol, f32));
  }
  // rela values at this lane's k positions, for all 3 relations
  float relv0[16], relv1[16], relv2[16];
#pragma unroll
  for (int j = 0; j < 8; ++j) {
    int k0 = quad * 8 + j;
    relv0[j] = rela_k[k0];        relv0[8 + j] = rela_k[32 + k0];
    relv1[j] = rela_k[64 + k0];   relv1[8 + j] = rela_k[96 + k0];
    relv2[j] = rela_k[128 + k0];  relv2[8 + j] = rela_k[160 + k0];
  }
  int n0 = blockIdx.x * 64;
  int row0 = n0 * 3;
#pragma unroll
  for (int tr = 0; tr < 12; ++tr) {
    int rl = tr * 16 + m;            // local A row
    int row = row0 + rl;
    int row_c = row < M3 ? row : 0;
    int i = rl % 3;                  // relation of this row (row0 % 3 == 0)
    const ushort8* pp = (const ushort8*)(prop + (size_t)row_c * 64 + quad * 8);
    ushort8 x0 = pp[0];              // k = quad*8 .. +7
    ushort8 x1 = pp[4];              // k+32
    short8 a0, a1;
#pragma unroll
    for (int j = 0; j < 8; ++j) {
      float r0 = (i == 0) ? relv0[j] : (i == 1 ? relv1[j] : relv2[j]);
      float r1 = (i == 0) ? relv0[8 + j] : (i == 1 ? relv1[8 + j] : relv2[8 + j]);
      a0[j] = (short)f2bits(bits2f(x0[j]) * r0);
      a1[j] = (short)f2bits(bits2f(x1[j]) * r1);
    }
    f32x4 acc = {0.f, 0.f, 0.f, 0.f};
    acc = __builtin_amdgcn_mfma_f32_16x16x32_bf16(a0, b0, acc, 0, 0, 0);
    acc = __builtin_amdgcn_mfma_f32_16x16x32_bf16(a1, b1, acc, 0, 0, 0);
    float v0 = acc[0]; v0 = v0 > 0.f ? v0 : 0.01f * v0;
    float v1 = acc[1]; v1 = v1 > 0.f ? v1 : 0.01f * v1;
    float v2 = acc[2]; v2 = v2 > 0.f ? v2 : 0.01f * v2;
    float v3 = acc[3]; v3 = v3 > 0.f ? v3 : 0.01f * v3;
    unsigned w0 = (unsigned)f2bits(v0) | ((unsigned)f2bits(v1) << 16);
    unsigned w1 = (unsigned)f2bits(v2) | ((unsigned)f2bits(v3) << 16);
    unsigned* p32 = (unsigned*)(est_t + wcol * 198 + tr * 16 + quad * 4);
    p32[0] = w0; p32[1] = w1;
  }
  __syncthreads();
  const float sc = 0.088388347648318447f;  // 1/sqrt(128)
  for (int jj = 0; jj < 16; ++jj) {
    int nl = wave * 16 + jj;
    int n = n0 + nl;
    if (n >= N_NODES) break;
    int rb = lane * 198 + 3 * nl;
    float e0 = bits2f(est_t[rb]);
    float e1 = bits2f(est_t[rb + 1]);
    float e2 = bits2f(est_t[rb + 2]);
    float s00 = wave_sum(e0 * e0);
    float s01 = wave_sum(e0 * e1);
    float s02 = wave_sum(e0 * e2);
    float s11 = wave_sum(e1 * e1);
    float s12 = wave_sum(e1 * e2);
    float s22 = wave_sum(e2 * e2);
    float o0 = attn_row(s00 * sc, s01 * sc, s02 * sc, e0, e1, e2);
    float o1 = attn_row(s01 * sc, s11 * sc, s12 * sc, e0, e1, e2);
    float o2 = attn_row(s02 * sc, s12 * sc, s22 * sc, e0, e1, e2);
    int base = n * RD + lane;
    ego_out[base] = __float2bfloat16(o0);
    ego_out[base + 64] = __float2bfloat16(o1);
    ego_out[base + 128] = __float2bfloat16(o2);
  }
}

// final: attention row 2, outputs, and MFMA GRU + scores.
// fmat stored bf16, row stride 72 (16B-aligned rows): LDS 28KB (was 51KB)
// -> 2x+ occupancy. Phase-2 A-frags via 2x ds_read_b128 (no conversion).
// Score partials accumulated over i in registers; single reduce per (tr,r).
__global__ __launch_bounds__(256, 4) void final_kernel(
    const bf16* __restrict__ ego0, const bf16* __restrict__ ego1,
    const bf16* __restrict__ ego2, const void* __restrict__ gru_w,
    const void* __restrict__ gru_b, const void* __restrict__ tra,
    const int* __restrict__ flag, void* out) {
  bool f32 = *flag != 0;
  __shared__ __align__(16) unsigned short fmatu[192 * 72];
  __shared__ float sc_lds[128];   // [64 nodes][2]
  int t = threadIdx.x, lane = t & 63, wave = t >> 6;
  int quad = lane >> 4, m = lane & 15;
  int wcol = wave * 16 + m;
  if (t < 128) sc_lds[t] = 0.f;
  // B-frags for gru_w[0..2]; biases; tra scalars (per-lane)
  short8 bw[3][2];
#pragma unroll
  for (int i = 0; i < 3; ++i)
#pragma unroll
    for (int j = 0; j < 8; ++j) {
      int k0 = quad * 8 + j;
      bw[i][0][j] = (short)f2bits(loadf(gru_w, i * 4096 + k0 * 64 + wcol, f32));
      bw[i][1][j] =
          (short)f2bits(loadf(gru_w, i * 4096 + (k0 + 32) * 64 + wcol, f32));
    }
  float bias0 = loadf(gru_b, wcol, f32);
  float bias1 = loadf(gru_b, 64 + wcol, f32);
  float bias2 = loadf(gru_b, 128 + wcol, f32);
  float ts0 = loadf(tra, wcol, f32);        // tra[0][:64]   (tgt -> sc1)
  float ts1 = loadf(tra, 64 + wcol, f32);   // tra[0][64:]   (aux1 -> sc1)
  float ts2 = loadf(tra, 128 + wcol, f32);  // tra[1][:64]   (tgt -> sc2)
  float ts3 = loadf(tra, 192 + wcol, f32);  // tra[1][64:]   (aux2 -> sc2)

  int n0 = blockIdx.x * 64;
  // Phase 1: attention + u/i outputs + fmat
  for (int jj = 0; jj < 16; ++jj) {
    int nl = wave * 16 + jj;
    int n = n0 + nl;
    float f0 = 0.f, f1 = 0.f, f2 = 0.f;
    if (n < N_NODES) {
      int b0i = n * RD + lane;
      float a0 = b2f(ego0[b0i]) + b2f(ego1[b0i]) + b2f(ego2[b0i]);
      float a1 =
          b2f(ego0[b0i + 64]) + b2f(ego1[b0i + 64]) + b2f(ego2[b0i + 64]);
      float a2 =
          b2f(ego0[b0i + 128]) + b2f(ego1[b0i + 128]) + b2f(ego2[b0i + 128]);
      float s20 = wave_sum(a2 * a0);
      float s21 = wave_sum(a2 * a1);
      float s22 = wave_sum(a2 * a2);
      float mid2 = attn_row(s20, s21, s22, a0, a1, a2);
      f0 = a0 * (1.f / 3.f);
      f1 = a1 * (1.f / 3.f);
      f2 = mid2 * (1.f / 3.f);
      if (n < N_USERS) {
        int ob = OFF_U + n * RD + lane;
        storef(out, ob, f0, f32);
        storef(out, ob + 64, f1, f32);
        storef(out, ob + 128, f2, f32);
      } else {
        int ob = OFF_I + (n - N_USERS) * RD + lane;
        storef(out, ob, f0, f32);
        storef(out, ob + 64, f1, f32);
        storef(out, ob + 128, f2, f32);
      }
    }
    fmatu[(0 * 64 + nl) * 72 + lane] = f2bits(f0);
    fmatu[(1 * 64 + nl) * 72 + lane] = f2bits(f1);
    fmatu[(2 * 64 + nl) * 72 + lane] = f2bits(f2);
  }
  __syncthreads();
  // Phase 2: 3 GEMMs (64x64 @ 64x64); score partials accumulated over i
  float p1a[4][4], p2a[4][4];
#pragma unroll
  for (int tr = 0; tr < 4; ++tr)
#pragma unroll
    for (int r = 0; r < 4; ++r) { p1a[tr][r] = 0.f; p2a[tr][r] = 0.f; }
#pragma unroll
  for (int i = 0; i < 3; ++i) {
    float bias = (i == 0) ? bias0 : (i == 1 ? bias1 : bias2);
#pragma unroll
    for (int tr = 0; tr < 4; ++tr) {
      int arow = (i * 64 + tr * 16 + m) * 72;
      short8 a0 = *(const short8*)(fmatu + arow + quad * 8);
      short8 a1 = *(const short8*)(fmatu + arow + 32 + quad * 8);
      f32x4 acc = {0.f, 0.f, 0.f, 0.f};
      acc = __builtin_amdgcn_mfma_f32_16x16x32_bf16(a0, bw[i][0], acc, 0, 0, 0);
      acc = __builtin_amdgcn_mfma_f32_16x16x32_bf16(a1, bw[i][1], acc, 0, 0, 0);
#pragma unroll
      for (int r = 0; r < 4; ++r) {
        int nl = tr * 16 + quad * 4 + r;
        float y = acc[r] + bias;
        float f = bits2f(fmatu[(i * 64 + nl) * 72 + wcol]);
        float prod = f * y;
        if (i == 0) p1a[tr][r] += prod * ts1;
        else if (i == 1) p2a[tr][r] += prod * ts3;
        else { p1a[tr][r] += prod * ts0; p2a[tr][r] += prod * ts2; }
      }
    }
  }
  // single reduce per (tr,r) over the 16 m-lanes, then LDS accumulate
#pragma unroll
  for (int tr = 0; tr < 4; ++tr)
#pragma unroll
    for (int r = 0; r < 4; ++r) {
      float p1 = p1a[tr][r], p2 = p2a[tr][r];
#pragma unroll
      for (int off = 1; off < 16; off <<= 1) {
        p1 += __shfl_xor(p1, off, 64);
        p2 += __shfl_xor(p2, off, 64);
      }
      if (m == 0) {
        int nl = tr * 16 + quad * 4 + r;
        atomicAdd(&sc_lds[nl * 2], p1);
        atomicAdd(&sc_lds[nl * 2 + 1], p2);
      }
    }
  __syncthreads();
  // Phase 3: score outputs
  if (t < 64) {
    int n = n0 + t;
    if (n < N_USERS) {
      storef(out, OFF_S1 + n, sc_lds[t * 2], f32);
      storef(out, OFF_S2 + n, sc_lds[t * 2 + 1], f32);
    }
  }
}

extern "C" void kernel_launch(void* const* d_in, const int* in_sizes, int n_in,
                              void* d_out, int out_size, void* d_ws,
                              size_t ws_size, hipStream_t stream) {
  const void* user_emb = d_in[0];
  const void* item_emb = d_in[1];
  const void* rel_emb = d_in[2];
  const void* W_gc = d_in[3];
  const void* W_rel = d_in[4];
  const void* gru_w = d_in[5];
  const void* gru_b = d_in[6];
  const void* tra = d_in[7];
  const void* adj_vals = d_in[8];
  const int* adj_rows = (const int*)d_in[9];
  const int* adj_cols = (const int*)d_in[10];

  // ws layout (~230 MB)
  int* flag = (int*)d_ws;
  float* wsf = (float*)d_ws;
  float* rela_f = wsf + 16;                       // 576 floats
  int* counts = (int*)(wsf + 1024);               // 300k
  int* offs = counts + M3;                        // 300k
  int* gcursor = offs + M3;                       // 512
  int* bcnt = gcursor + 512;                      // 512
  int* bbase = bcnt + 512;                        // 512
  u64* abuf = (u64*)(bbase + 512);                // 4.8M u64 (8B-aligned)
  int2* sedge = (int2*)(abuf + NE3);              // 4.8M int2
  bf16* ego0 = (bf16*)(sedge + NE3);              // 19.2M bf16
  bf16* ego1 = ego0 + (size_t)N_NODES * RD;
  bf16* ego2 = ego1 + (size_t)N_NODES * RD;
  bf16* prop = ego2 + (size_t)N_NODES * RD;

  const int nbE = (NE3 + 4095) / 4096;            // 1172

  detect_kernel<<<1, 256, 0, stream>>>((const unsigned short*)user_emb, flag);
  rela_kernel<<<1, 192, 0, stream>>>(rel_emb, W_rel, flag, rela_f, d_out);
  zero_row_kernel<<<1, 192, 0, stream>>>(d_out, flag);
  init_kernel<<<(N_NODES * RD / 4 + 255) / 256, 256, 0, stream>>>(
      user_emb, item_emb, flag, ego0);

  (void)hipMemsetAsync(bcnt, 0, 512 * sizeof(int), stream);
  bhist_kernel<<<nbE, 256, 0, stream>>>(adj_rows, bcnt);
  bscan_kernel<<<1, 512, 0, stream>>>(bcnt, gcursor, bbase);
  passA_kernel<<<nbE, 256, 0, stream>>>(
      adj_rows, adj_cols, adj_vals, flag, gcursor, abuf);
  passB_kernel<<<NBUCK, 256, 0, stream>>>(abuf, bbase, bcnt, offs, counts,
                                          sedge);

  gather_kernel<<<dim3(N_NODES / 4, 3), 256, 0, stream>>>(
      sedge, counts, offs, ego0, prop);
  transform_attn_kernel<<<(N_NODES + 63) / 64, 256, 0, stream>>>(
      prop, rela_f, W_gc, 0, flag, ego1);
  gather_kernel<<<dim3(N_NODES / 4, 3), 256, 0, stream>>>(
      sedge, counts, offs, ego1, prop);
  transform_attn_kernel<<<(N_NODES + 63) / 64, 256, 0, stream>>>(
      prop, rela_f + 192, W_gc, 4096, flag, ego2);

  final_kernel<<<(N_NODES + 63) / 64, 256, 0, stream>>>(
      ego0, ego1, ego2, gru_w, gru_b, tra, flag, d_out);
}